// Round 4
// baseline (282.012 us; speedup 1.0000x reference)
//
#include <hip/hip_runtime.h>
#include <cstdint>
#include <cstddef>

// ---------------------------------------------------------------------------
// GCN encoder: z = GCN3( relu(GCN2( relu(GCN1( LN(x) )) )) )
// R15: LN stats fused into GEMM1. Each gemm block computes mean/rsqrt for its
//      64 rows in a register pass (4 thr/row, 2 shfl_xor) -> LDS, then the
//      k-loop A-staging normalizes using LDS stats; the A re-read hits L2/L3.
//      This removes the second 51.2 MB HBM read of x and prep's ln_stats
//      section (prep now: hist x256 + wsplit only, ~3 us). mu/rs buffers
//      deleted. Everything else unchanged from R14 (280.7 us).
// ---------------------------------------------------------------------------

typedef __attribute__((ext_vector_type(8))) __bf16 bf16x8;
typedef __attribute__((ext_vector_type(4))) float f32x4;
typedef _Float16 half_t;
typedef __attribute__((ext_vector_type(8))) _Float16 half8_t;

#define NHIST 256

// ---------------- prep: hist x256 | wsplit x3, by block range --------------
__global__ __launch_bounds__(256) void prep_misc(
    const int* __restrict__ dst,
    const float* __restrict__ W1, const float* __restrict__ W2,
    const float* __restrict__ W3,
    int* __restrict__ bcnt_multi,
    unsigned short* __restrict__ W1t_hi, unsigned short* __restrict__ W1t_lo,
    unsigned short* __restrict__ W2t_hi, unsigned short* __restrict__ W2t_lo,
    unsigned short* __restrict__ W3t_hi, unsigned short* __restrict__ W3t_lo,
    int E) {
  int blk = blockIdx.x;
  int tid = threadIdx.x;
  if (blk < NHIST) {
    // slice histogram: grid-stride, one private LDS hist per block,
    // write-only slice output (no global zeroing, no global atomics)
    __shared__ int h[256];
    h[tid] = 0;
    __syncthreads();
    for (int e = blk * 256 + tid; e < E; e += NHIST * 256)
      atomicAdd(&h[dst[e] >> 8], 1);
    __syncthreads();
    bcnt_multi[blk * 256 + tid] = h[tid];
    return;
  }
  int idx = (blk - NHIST) * 256 + tid;
  const float* W;
  unsigned short *Th, *Tl;
  int K, NOUT;
  if (idx < 32768) {
    W = W1; Th = W1t_hi; Tl = W1t_lo; K = 256; NOUT = 128;
  } else if (idx < 49152) {
    idx -= 32768;
    W = W2; Th = W2t_hi; Tl = W2t_lo; K = 128; NOUT = 128;
  } else {
    idx -= 49152;
    W = W3; Th = W3t_hi; Tl = W3t_lo; K = 128; NOUT = 64;
  }
  int k = idx / NOUT, c = idx % NOUT;
  float v = W[idx];
  __bf16 h = (__bf16)v;
  __bf16 l = (__bf16)(v - (float)h);
  Th[(size_t)c * K + k] = __builtin_bit_cast(unsigned short, h);
  Tl[(size_t)c * K + k] = __builtin_bit_cast(unsigned short, l);
}

// ---------------- scan: sum 256 slices, exclusive prefix ----------------
__global__ __launch_bounds__(256) void scan_buckets(const int* __restrict__ bcnt_multi,
                                                    int* __restrict__ bbase,
                                                    int* __restrict__ bcur, int NB, int E) {
  __shared__ int tmp[256];
  int t = threadIdx.x;
  int v = 0;
  for (int h = 0; h < NHIST; ++h) v += bcnt_multi[h * 256 + t];
  tmp[t] = v;
  __syncthreads();
  for (int off = 1; off < 256; off <<= 1) {
    int x = (t >= off) ? tmp[t - off] : 0;
    __syncthreads();
    tmp[t] += x;
    __syncthreads();
  }
  int excl = tmp[t] - v;
  if (t < NB) { bbase[t] = excl; bcur[t] = excl; }
  if (t == 0) bbase[NB] = E;
}

#define CHUNK 4096
// record = (dst << 16) | src  (both < 65536)
__global__ __launch_bounds__(256) void scatter_bins(const int* __restrict__ src,
                                                    const int* __restrict__ dst,
                                                    int* __restrict__ bcur,
                                                    unsigned int* __restrict__ binned, int E) {
  __shared__ unsigned int recs[CHUNK];  // 16 KB
  __shared__ int hist[256], lbase[256], resv[256], cur[256];
  int t = threadIdx.x;
  int e0 = blockIdx.x * CHUNK;
  if (e0 >= E) return;
  int len = min(CHUNK, E - e0);
  hist[t] = 0;
  cur[t] = 0;
  __syncthreads();
  for (int i = t; i < len; i += 256) atomicAdd(&hist[dst[e0 + i] >> 8], 1);
  __syncthreads();
  int v = hist[t];
  lbase[t] = v;
  __syncthreads();
  for (int off = 1; off < 256; off <<= 1) {
    int x = (t >= off) ? lbase[t - off] : 0;
    __syncthreads();
    lbase[t] += x;
    __syncthreads();
  }
  int myexcl = lbase[t] - v;
  if (v) resv[t] = atomicAdd(&bcur[t], v);
  __syncthreads();
  lbase[t] = myexcl;
  __syncthreads();
  for (int i = t; i < len; i += 256) {
    int d = dst[e0 + i], s = src[e0 + i];
    int b = d >> 8;
    int r = atomicAdd(&cur[b], 1);
    recs[lbase[b] + r] = ((unsigned int)d << 16) | (unsigned int)s;
  }
  __syncthreads();
  for (int i = t; i < len; i += 256) {
    unsigned int rc = recs[i];
    int b = rc >> 24;
    binned[resv[b] + (i - lbase[b])] = rc;
  }
}

#define MAXB 8192
// counting-sort one 256-node bucket; binned re-read from L2 (no record LDS)
__global__ __launch_bounds__(256) void sort_bucket(const unsigned int* __restrict__ binned,
                                                   const int* __restrict__ bbase,
                                                   int* __restrict__ srcs,
                                                   int* __restrict__ offs,
                                                   float* __restrict__ dinv,
                                                   int N, int NB, int E) {
  __shared__ int sstage[MAXB];  // 32 KB
  __shared__ int hist[256], nbase[256], cur[256], tmp[256];
  int b = blockIdx.x, t = threadIdx.x;
  int base = bbase[b], end = bbase[b + 1];
  int L = end - base;
  if (L > MAXB) L = MAXB;
  hist[t] = 0;
  __syncthreads();
  for (int i = t; i < L; i += 256)
    atomicAdd(&hist[(binned[base + i] >> 16) & 255], 1);
  __syncthreads();
  int v = hist[t];
  tmp[t] = v;
  __syncthreads();
  for (int off = 1; off < 256; off <<= 1) {
    int x = (t >= off) ? tmp[t - off] : 0;
    __syncthreads();
    tmp[t] += x;
    __syncthreads();
  }
  int excl = tmp[t] - v;
  nbase[t] = excl;
  cur[t] = excl;
  int node = (b << 8) + t;
  if (node < N) {
    offs[node] = base + excl;
    dinv[node] = rsqrtf(1.0f + (float)v);
  }
  if (b == NB - 1 && t == 0) offs[N] = E;
  __syncthreads();
  for (int i = t; i < L; i += 256) {
    unsigned int p = binned[base + i];
    int ld = (p >> 16) & 255;
    int slot = atomicAdd(&cur[ld], 1);
    sstage[slot] = (int)(p & 0xFFFFu);
  }
  __syncthreads();
  for (int i = t; i < L; i += 256) srcs[base + i] = sstage[i];
}

// ---------------- single-buffer bf16x3 MFMA GEMM, LN stats fused -----------
template <int K, int NOUT, bool LN, bool A_FP16>
__launch_bounds__(256)
__global__ void gemm_mfma(const void* __restrict__ Avoid,
                          const unsigned short* __restrict__ Wt_hi,
                          const unsigned short* __restrict__ Wt_lo,
                          const float* __restrict__ gamma, const float* __restrict__ beta,
                          half_t* __restrict__ out, int nrows) {
  constexpr int BM = 64, BK = 32;
  constexpr int NT = NOUT / 16;
  __shared__ unsigned short As_hi[BM][BK];
  __shared__ unsigned short As_lo[BM][BK];
  __shared__ unsigned short Bs_hi[NOUT][BK];
  __shared__ unsigned short Bs_lo[NOUT][BK];
  __shared__ float mu_s[BM];
  __shared__ float rs_s[BM];

  const int tid = threadIdx.x;
  const int lane = tid & 63;
  const int w = tid >> 6;
  const int quad = lane >> 4;
  const int l16 = lane & 15;
  const int row0 = blockIdx.x * BM;

  if (LN) {
    // pass 1: per-row LN stats. 4 threads per row, K/16 float4 each.
    const float* A = (const float*)Avoid;
    int r = tid >> 2;
    int part = tid & 3;
    int grow = row0 + r;
    if (grow > nrows - 1) grow = nrows - 1;
    const float4* rp = (const float4*)(A + (size_t)grow * K);
    float s = 0.f, s2 = 0.f;
#pragma unroll
    for (int j = 0; j < K / 16; ++j) {
      float4 v = rp[part * (K / 16) + j];
      s += v.x + v.y + v.z + v.w;
      s2 += v.x * v.x + v.y * v.y + v.z * v.z + v.w * v.w;
    }
    s += __shfl_xor(s, 1);
    s += __shfl_xor(s, 2);
    s2 += __shfl_xor(s2, 1);
    s2 += __shfl_xor(s2, 2);
    if (part == 0) {
      float m = s * (1.0f / (float)K);
      float var = s2 * (1.0f / (float)K) - m * m;
      mu_s[r] = m;
      rs_s[r] = rsqrtf(var + 1e-5f);
    }
    __syncthreads();
  }

  f32x4 acc[NT];
#pragma unroll
  for (int t = 0; t < NT; ++t) acc[t] = (f32x4){0.f, 0.f, 0.f, 0.f};

  for (int k0 = 0; k0 < K; k0 += BK) {
    if (!A_FP16) {
      const float* A = (const float*)Avoid;
#pragma unroll
      for (int i = 0; i < 2; ++i) {
        int r = i * 32 + (tid >> 3);
        int c4 = (tid & 7) * 4;
        int grow = row0 + r;
        if (grow > nrows - 1) grow = nrows - 1;
        float4 v = *(const float4*)&A[(size_t)grow * K + k0 + c4];
        if (LN) {
          float m = mu_s[r], s = rs_s[r];
          float4 g = *(const float4*)&gamma[k0 + c4];
          float4 b = *(const float4*)&beta[k0 + c4];
          v.x = (v.x - m) * s * g.x + b.x;
          v.y = (v.y - m) * s * g.y + b.y;
          v.z = (v.z - m) * s * g.z + b.z;
          v.w = (v.w - m) * s * g.w + b.w;
        }
        float vv[4] = {v.x, v.y, v.z, v.w};
#pragma unroll
        for (int j = 0; j < 4; ++j) {
          __bf16 h = (__bf16)vv[j];
          __bf16 l = (__bf16)(vv[j] - (float)h);
          As_hi[r][c4 + j] = __builtin_bit_cast(unsigned short, h);
          As_lo[r][c4 + j] = __builtin_bit_cast(unsigned short, l);
        }
      }
    } else {
      const half_t* A = (const half_t*)Avoid;
      int r = tid >> 2;
      int c8 = (tid & 3) * 8;
      int grow = row0 + r;
      if (grow > nrows - 1) grow = nrows - 1;
      half8_t v = *(const half8_t*)&A[(size_t)grow * K + k0 + c8];
#pragma unroll
      for (int j = 0; j < 8; ++j) {
        float f = (float)v[j];
        __bf16 h = (__bf16)f;
        __bf16 l = (__bf16)(f - (float)h);
        As_hi[r][c8 + j] = __builtin_bit_cast(unsigned short, h);
        As_lo[r][c8 + j] = __builtin_bit_cast(unsigned short, l);
      }
    }
#pragma unroll
    for (int i = 0; i < NOUT / 64; ++i) {
      int n = i * 64 + (tid >> 2);
      int c8 = (tid & 3) * 8;
      *(uint4*)&Bs_hi[n][c8] = *(const uint4*)&Wt_hi[(size_t)n * K + k0 + c8];
      *(uint4*)&Bs_lo[n][c8] = *(const uint4*)&Wt_lo[(size_t)n * K + k0 + c8];
    }
    __syncthreads();

    bf16x8 ah = *(const bf16x8*)&As_hi[w * 16 + l16][quad * 8];
    bf16x8 al = *(const bf16x8*)&As_lo[w * 16 + l16][quad * 8];
#pragma unroll
    for (int t = 0; t < NT; ++t) {
      bf16x8 bh = *(const bf16x8*)&Bs_hi[t * 16 + l16][quad * 8];
      bf16x8 bl = *(const bf16x8*)&Bs_lo[t * 16 + l16][quad * 8];
      acc[t] = __builtin_amdgcn_mfma_f32_16x16x32_bf16(ah, bh, acc[t], 0, 0, 0);
      acc[t] = __builtin_amdgcn_mfma_f32_16x16x32_bf16(al, bh, acc[t], 0, 0, 0);
      acc[t] = __builtin_amdgcn_mfma_f32_16x16x32_bf16(ah, bl, acc[t], 0, 0, 0);
    }
    __syncthreads();
  }

#pragma unroll
  for (int t = 0; t < NT; ++t) {
#pragma unroll
    for (int r = 0; r < 4; ++r) {
      int grow = row0 + w * 16 + quad * 4 + r;
      if (grow < nrows) out[(size_t)grow * NOUT + t * 16 + l16] = (half_t)acc[t][r];
    }
  }
}

// ---------------- aggregation: quarter-wave gathers, srcs + dinv[src] ------
__global__ __launch_bounds__(256) void agg128_h(const half_t* __restrict__ t,
                                                const int* __restrict__ offs,
                                                const int* __restrict__ srcs,
                                                const float* __restrict__ dinv,
                                                const float* __restrict__ bias,
                                                half_t* __restrict__ out, int n) {
  int gid = blockIdx.x * blockDim.x + threadIdx.x;
  int node = gid >> 6, lane = gid & 63;
  if (node >= n) return;
  int qw = lane >> 4;
  int fl = lane & 15;
  int e0 = offs[node], e1 = offs[node + 1];
  float acc[8] = {0.f, 0.f, 0.f, 0.f, 0.f, 0.f, 0.f, 0.f};
  int e = e0 + qw;
  for (; e + 12 < e1; e += 16) {
    int sa = srcs[e], sb = srcs[e + 4], sc = srcs[e + 8], sd = srcs[e + 12];
    float wa = dinv[sa], wb = dinv[sb], wc = dinv[sc], wd = dinv[sd];
    half8_t va = *(const half8_t*)(t + ((size_t)sa << 7) + fl * 8);
    half8_t vb = *(const half8_t*)(t + ((size_t)sb << 7) + fl * 8);
    half8_t vc = *(const half8_t*)(t + ((size_t)sc << 7) + fl * 8);
    half8_t vd = *(const half8_t*)(t + ((size_t)sd << 7) + fl * 8);
#pragma unroll
    for (int j = 0; j < 8; ++j) {
      acc[j] = fmaf(wa, (float)va[j], acc[j]);
      acc[j] = fmaf(wb, (float)vb[j], acc[j]);
      acc[j] = fmaf(wc, (float)vc[j], acc[j]);
      acc[j] = fmaf(wd, (float)vd[j], acc[j]);
    }
  }
  for (; e < e1; e += 4) {
    int s = srcs[e];
    float w = dinv[s];
    half8_t v = *(const half8_t*)(t + ((size_t)s << 7) + fl * 8);
#pragma unroll
    for (int j = 0; j < 8; ++j) acc[j] = fmaf(w, (float)v[j], acc[j]);
  }
#pragma unroll
  for (int j = 0; j < 8; ++j) {
    acc[j] += __shfl_xor(acc[j], 16);
    acc[j] += __shfl_xor(acc[j], 32);
  }
  if (qw == 0) {
    float di = dinv[node];
    float dii = di * di;
    half8_t sv = *(const half8_t*)(t + ((size_t)node << 7) + fl * 8);
    float4 b0 = *(const float4*)(bias + fl * 8);
    float4 b1 = *(const float4*)(bias + fl * 8 + 4);
    float bb[8] = {b0.x, b0.y, b0.z, b0.w, b1.x, b1.y, b1.z, b1.w};
    half8_t o;
#pragma unroll
    for (int j = 0; j < 8; ++j) {
      float v = di * acc[j] + dii * (float)sv[j] + bb[j];
      o[j] = (half_t)fmaxf(v, 0.f);
    }
    *(half8_t*)(out + ((size_t)node << 7) + fl * 8) = o;
  }
}

__global__ __launch_bounds__(256) void agg64_h(const half_t* __restrict__ t,
                                               const int* __restrict__ offs,
                                               const int* __restrict__ srcs,
                                               const float* __restrict__ dinv,
                                               const float* __restrict__ bias,
                                               float* __restrict__ out, int n) {
  int gid = blockIdx.x * blockDim.x + threadIdx.x;
  int node = gid >> 6, lane = gid & 63;
  if (node >= n) return;
  int og = lane >> 3;
  int fl = lane & 7;
  int e0 = offs[node], e1 = offs[node + 1];
  float acc[8] = {0.f, 0.f, 0.f, 0.f, 0.f, 0.f, 0.f, 0.f};
  int e = e0 + og;
  for (; e + 8 < e1; e += 16) {
    int sa = srcs[e], sb = srcs[e + 8];
    float wa = dinv[sa], wb = dinv[sb];
    half8_t va = *(const half8_t*)(t + ((size_t)sa << 6) + fl * 8);
    half8_t vb = *(const half8_t*)(t + ((size_t)sb << 6) + fl * 8);
#pragma unroll
    for (int j = 0; j < 8; ++j) {
      acc[j] = fmaf(wa, (float)va[j], acc[j]);
      acc[j] = fmaf(wb, (float)vb[j], acc[j]);
    }
  }
  for (; e < e1; e += 8) {
    int s = srcs[e];
    float w = dinv[s];
    half8_t v = *(const half8_t*)(t + ((size_t)s << 6) + fl * 8);
#pragma unroll
    for (int j = 0; j < 8; ++j) acc[j] = fmaf(w, (float)v[j], acc[j]);
  }
#pragma unroll
  for (int j = 0; j < 8; ++j) {
    acc[j] += __shfl_xor(acc[j], 8);
    acc[j] += __shfl_xor(acc[j], 16);
    acc[j] += __shfl_xor(acc[j], 32);
  }
  if (og == 0) {
    float di = dinv[node];
    float dii = di * di;
    half8_t sv = *(const half8_t*)(t + ((size_t)node << 6) + fl * 8);
    float4 b0 = *(const float4*)(bias + fl * 8);
    float4 b1 = *(const float4*)(bias + fl * 8 + 4);
    float bb[8] = {b0.x, b0.y, b0.z, b0.w, b1.x, b1.y, b1.z, b1.w};
    float ov[8];
#pragma unroll
    for (int j = 0; j < 8; ++j) ov[j] = di * acc[j] + dii * (float)sv[j] + bb[j];
    *(float4*)(out + ((size_t)node << 6) + fl * 8) = make_float4(ov[0], ov[1], ov[2], ov[3]);
    *(float4*)(out + ((size_t)node << 6) + fl * 8 + 4) = make_float4(ov[4], ov[5], ov[6], ov[7]);
  }
}

extern "C" void kernel_launch(void* const* d_in, const int* in_sizes, int n_in,
                              void* d_out, int out_size, void* d_ws, size_t ws_size,
                              hipStream_t stream) {
  const float* x = (const float*)d_in[0];
  const int* ei = (const int*)d_in[1];
  const float* gamma = (const float*)d_in[2];
  const float* beta = (const float*)d_in[3];
  const float* W1 = (const float*)d_in[4];
  const float* b1 = (const float*)d_in[5];
  const float* W2 = (const float*)d_in[6];
  const float* b2 = (const float*)d_in[7];
  const float* W3 = (const float*)d_in[8];
  const float* b3 = (const float*)d_in[9];
  float* out = (float*)d_out;

  const int N = in_sizes[0] / 256;  // 50000 < 65536: packed records valid
  const int E = in_sizes[1] / 2;
  const int* src = ei;
  const int* dst = ei + E;
  const int NB = (N + 255) >> 8;

  char* ws = (char*)d_ws;
  auto alloc = [&](size_t bytes) -> char* {
    char* p = ws;
    ws += (bytes + 255) & ~(size_t)255;
    return p;
  };
  int* bcnt_multi = (int*)alloc(NHIST * 256 * 4);
  int* bbase = (int*)alloc(257 * 4);
  int* bcur = (int*)alloc(256 * 4);
  unsigned int* binned = (unsigned int*)alloc((size_t)E * 4);
  int* srcs = (int*)alloc((size_t)E * 4);
  int* offs = (int*)alloc((size_t)(N + 1) * 4);
  float* dinv = (float*)alloc((size_t)N * 4);
  half_t* t = (half_t*)alloc((size_t)N * 128 * 2);
  half_t* h = (half_t*)alloc((size_t)N * 128 * 2);
  unsigned short* W1t_hi = (unsigned short*)alloc(256 * 128 * 2);
  unsigned short* W1t_lo = (unsigned short*)alloc(256 * 128 * 2);
  unsigned short* W2t_hi = (unsigned short*)alloc(128 * 128 * 2);
  unsigned short* W2t_lo = (unsigned short*)alloc(128 * 128 * 2);
  unsigned short* W3t_hi = (unsigned short*)alloc(128 * 64 * 2);
  unsigned short* W3t_lo = (unsigned short*)alloc(128 * 64 * 2);

  // ---- prep: hist x256 + wsplit x3 in one launch ----
  prep_misc<<<NHIST + 224, 256, 0, stream>>>(
      dst, W1, W2, W3, bcnt_multi, W1t_hi, W1t_lo, W2t_hi, W2t_lo,
      W3t_hi, W3t_lo, E);

  // ---- CSR build ----
  scan_buckets<<<1, 256, 0, stream>>>(bcnt_multi, bbase, bcur, NB, E);
  scatter_bins<<<(E + CHUNK - 1) / CHUNK, 256, 0, stream>>>(src, dst, bcur, binned, E);
  sort_bucket<<<NB, 256, 0, stream>>>(binned, bbase, srcs, offs, dinv, N, NB, E);

  const int gemm_blocks = (N + 63) / 64;
  const int agg_blocks = (N + 3) / 4;

  // ---- layer 1 ----
  gemm_mfma<256, 128, true, false><<<gemm_blocks, 256, 0, stream>>>(
      x, W1t_hi, W1t_lo, gamma, beta, t, N);
  agg128_h<<<agg_blocks, 256, 0, stream>>>(t, offs, srcs, dinv, b1, h, N);

  // ---- layer 2 ----
  gemm_mfma<128, 128, false, true><<<gemm_blocks, 256, 0, stream>>>(
      h, W2t_hi, W2t_lo, nullptr, nullptr, t, N);
  agg128_h<<<agg_blocks, 256, 0, stream>>>(t, offs, srcs, dinv, b2, h, N);

  // ---- layer 3 ----
  gemm_mfma<128, 64, false, true><<<gemm_blocks, 256, 0, stream>>>(
      h, W3t_hi, W3t_lo, nullptr, nullptr, t, N);
  agg64_h<<<agg_blocks, 256, 0, stream>>>(t, offs, srcs, dinv, b3, out, N);
}

// Round 5
// 271.455 us; speedup vs baseline: 1.0389x; 1.0389x over previous
//
#include <hip/hip_runtime.h>
#include <cstdint>
#include <cstddef>

// ---------------------------------------------------------------------------
// GCN encoder: z = GCN3( relu(GCN2( relu(GCN1( LN(x) )) )) )
// R16: two fixes from R15 counters (gemm1: 42.8us, MfmaUtil 7%, occ 22%,
//      1.8M LDS bank conflicts -> latency-bound + 8-way conflicts):
//  A) GEMM LDS tiles padded to BK+8 (row stride 80B): 8-way ds_read_b128
//     conflicts -> 2-way (free). All three layers.
//  B) GEMM1 split in half and fused into the scatter_bins and sort_bucket
//     launches (independent work; block-range dispatch, union smem via
//     char[] passed to device bodies). Latency-bound GEMM1 hides under the
//     BW-bound CSR build. 8 launches total.
// ---------------------------------------------------------------------------

typedef __attribute__((ext_vector_type(8))) __bf16 bf16x8;
typedef __attribute__((ext_vector_type(4))) float f32x4;
typedef _Float16 half_t;
typedef __attribute__((ext_vector_type(8))) _Float16 half8_t;

#define NHIST 256
#define CHUNK 4096
#define MAXB 8192

// ---------------- prep: hist x256 | wsplit x3, by block range --------------
__global__ __launch_bounds__(256) void prep_misc(
    const int* __restrict__ dst,
    const float* __restrict__ W1, const float* __restrict__ W2,
    const float* __restrict__ W3,
    int* __restrict__ bcnt_multi,
    unsigned short* __restrict__ W1t_hi, unsigned short* __restrict__ W1t_lo,
    unsigned short* __restrict__ W2t_hi, unsigned short* __restrict__ W2t_lo,
    unsigned short* __restrict__ W3t_hi, unsigned short* __restrict__ W3t_lo,
    int E) {
  int blk = blockIdx.x;
  int tid = threadIdx.x;
  if (blk < NHIST) {
    __shared__ int h[256];
    h[tid] = 0;
    __syncthreads();
    for (int e = blk * 256 + tid; e < E; e += NHIST * 256)
      atomicAdd(&h[dst[e] >> 8], 1);
    __syncthreads();
    bcnt_multi[blk * 256 + tid] = h[tid];
    return;
  }
  int idx = (blk - NHIST) * 256 + tid;
  const float* W;
  unsigned short *Th, *Tl;
  int K, NOUT;
  if (idx < 32768) {
    W = W1; Th = W1t_hi; Tl = W1t_lo; K = 256; NOUT = 128;
  } else if (idx < 49152) {
    idx -= 32768;
    W = W2; Th = W2t_hi; Tl = W2t_lo; K = 128; NOUT = 128;
  } else {
    idx -= 49152;
    W = W3; Th = W3t_hi; Tl = W3t_lo; K = 128; NOUT = 64;
  }
  int k = idx / NOUT, c = idx % NOUT;
  float v = W[idx];
  __bf16 h = (__bf16)v;
  __bf16 l = (__bf16)(v - (float)h);
  Th[(size_t)c * K + k] = __builtin_bit_cast(unsigned short, h);
  Tl[(size_t)c * K + k] = __builtin_bit_cast(unsigned short, l);
}

// ---------------- scan: sum 256 slices, exclusive prefix ----------------
__global__ __launch_bounds__(256) void scan_buckets(const int* __restrict__ bcnt_multi,
                                                    int* __restrict__ bbase,
                                                    int* __restrict__ bcur, int NB, int E) {
  __shared__ int tmp[256];
  int t = threadIdx.x;
  int v = 0;
  for (int h = 0; h < NHIST; ++h) v += bcnt_multi[h * 256 + t];
  tmp[t] = v;
  __syncthreads();
  for (int off = 1; off < 256; off <<= 1) {
    int x = (t >= off) ? tmp[t - off] : 0;
    __syncthreads();
    tmp[t] += x;
    __syncthreads();
  }
  int excl = tmp[t] - v;
  if (t < NB) { bbase[t] = excl; bcur[t] = excl; }
  if (t == 0) bbase[NB] = E;
}

// ---------------- scatter body (smem: 20480 B) ----------------
// record = (dst << 16) | src  (both < 65536)
__device__ __forceinline__ void scatter_body(char* smem_raw, int bid,
                                             const int* __restrict__ src,
                                             const int* __restrict__ dst,
                                             int* __restrict__ bcur,
                                             unsigned int* __restrict__ binned, int E) {
  unsigned int* recs = (unsigned int*)smem_raw;          // 16384 B
  int* hist = (int*)(smem_raw + 16384);
  int* lbase = hist + 256;
  int* resv = lbase + 256;
  int* cur = resv + 256;
  int t = threadIdx.x;
  int e0 = bid * CHUNK;
  if (e0 >= E) return;
  int len = min(CHUNK, E - e0);
  hist[t] = 0;
  cur[t] = 0;
  __syncthreads();
  for (int i = t; i < len; i += 256) atomicAdd(&hist[dst[e0 + i] >> 8], 1);
  __syncthreads();
  int v = hist[t];
  lbase[t] = v;
  __syncthreads();
  for (int off = 1; off < 256; off <<= 1) {
    int x = (t >= off) ? lbase[t - off] : 0;
    __syncthreads();
    lbase[t] += x;
    __syncthreads();
  }
  int myexcl = lbase[t] - v;
  if (v) resv[t] = atomicAdd(&bcur[t], v);
  __syncthreads();
  lbase[t] = myexcl;
  __syncthreads();
  for (int i = t; i < len; i += 256) {
    int d = dst[e0 + i], s = src[e0 + i];
    int b = d >> 8;
    int r = atomicAdd(&cur[b], 1);
    recs[lbase[b] + r] = ((unsigned int)d << 16) | (unsigned int)s;
  }
  __syncthreads();
  for (int i = t; i < len; i += 256) {
    unsigned int rc = recs[i];
    int b = rc >> 24;
    binned[resv[b] + (i - lbase[b])] = rc;
  }
}

// ---------------- sort body (smem: 36864 B) ----------------
__device__ __forceinline__ void sort_body(char* smem_raw, int b,
                                          const unsigned int* __restrict__ binned,
                                          const int* __restrict__ bbase,
                                          int* __restrict__ srcs,
                                          int* __restrict__ offs,
                                          float* __restrict__ dinv,
                                          int N, int NB, int E) {
  int* sstage = (int*)smem_raw;                           // 32768 B
  int* hist = (int*)(smem_raw + 32768);
  int* nbase = hist + 256;
  int* cur = nbase + 256;
  int* tmp = cur + 256;
  int t = threadIdx.x;
  int base = bbase[b], end = bbase[b + 1];
  int L = end - base;
  if (L > MAXB) L = MAXB;
  hist[t] = 0;
  __syncthreads();
  for (int i = t; i < L; i += 256)
    atomicAdd(&hist[(binned[base + i] >> 16) & 255], 1);
  __syncthreads();
  int v = hist[t];
  tmp[t] = v;
  __syncthreads();
  for (int off = 1; off < 256; off <<= 1) {
    int x = (t >= off) ? tmp[t - off] : 0;
    __syncthreads();
    tmp[t] += x;
    __syncthreads();
  }
  int excl = tmp[t] - v;
  nbase[t] = excl;
  cur[t] = excl;
  int node = (b << 8) + t;
  if (node < N) {
    offs[node] = base + excl;
    dinv[node] = rsqrtf(1.0f + (float)v);
  }
  if (b == NB - 1 && t == 0) offs[N] = E;
  __syncthreads();
  for (int i = t; i < L; i += 256) {
    unsigned int p = binned[base + i];
    int ld = (p >> 16) & 255;
    int slot = atomicAdd(&cur[ld], 1);
    sstage[slot] = (int)(p & 0xFFFFu);
  }
  __syncthreads();
  for (int i = t; i < L; i += 256) srcs[base + i] = sstage[i];
}

// ---------------- GEMM body: bf16x3 MFMA, BK+8-padded LDS ------------------
// smem bytes: 64*40*4 (A hi+lo) + NOUT*40*4 (B hi+lo) + 512 (stats)
template <int K, int NOUT, bool LN, bool A_FP16>
__device__ __forceinline__ void gemm_body(char* smem_raw, int gbid,
                                          const void* __restrict__ Avoid,
                                          const unsigned short* __restrict__ Wt_hi,
                                          const unsigned short* __restrict__ Wt_lo,
                                          const float* __restrict__ gamma,
                                          const float* __restrict__ beta,
                                          half_t* __restrict__ out, int nrows) {
  constexpr int BM = 64, BK = 32, BKP = BK + 8;
  constexpr int NT = NOUT / 16;
  unsigned short* As_hi = (unsigned short*)smem_raw;          // 64*40*2 = 5120
  unsigned short* As_lo = As_hi + BM * BKP;                   // 5120
  unsigned short* Bs_hi = As_lo + BM * BKP;                   // NOUT*40*2
  unsigned short* Bs_lo = Bs_hi + NOUT * BKP;                 // NOUT*40*2
  float* mu_s = (float*)(Bs_lo + NOUT * BKP);
  float* rs_s = mu_s + BM;

  const int tid = threadIdx.x;
  const int lane = tid & 63;
  const int w = tid >> 6;
  const int quad = lane >> 4;
  const int l16 = lane & 15;
  const int row0 = gbid * BM;

  if constexpr (LN) {
    // pass 1: per-row LN stats. 4 threads per row, K/16 float4 each.
    const float* A = (const float*)Avoid;
    int r = tid >> 2;
    int part = tid & 3;
    int grow = row0 + r;
    if (grow > nrows - 1) grow = nrows - 1;
    const float4* rp = (const float4*)(A + (size_t)grow * K);
    float s = 0.f, s2 = 0.f;
#pragma unroll
    for (int j = 0; j < K / 16; ++j) {
      float4 v = rp[part * (K / 16) + j];
      s += v.x + v.y + v.z + v.w;
      s2 += v.x * v.x + v.y * v.y + v.z * v.z + v.w * v.w;
    }
    s += __shfl_xor(s, 1);
    s += __shfl_xor(s, 2);
    s2 += __shfl_xor(s2, 1);
    s2 += __shfl_xor(s2, 2);
    if (part == 0) {
      float m = s * (1.0f / (float)K);
      float var = s2 * (1.0f / (float)K) - m * m;
      mu_s[r] = m;
      rs_s[r] = rsqrtf(var + 1e-5f);
    }
    __syncthreads();
  }

  f32x4 acc[NT];
#pragma unroll
  for (int t = 0; t < NT; ++t) acc[t] = (f32x4){0.f, 0.f, 0.f, 0.f};

  for (int k0 = 0; k0 < K; k0 += BK) {
    if constexpr (!A_FP16) {
      const float* A = (const float*)Avoid;
#pragma unroll
      for (int i = 0; i < 2; ++i) {
        int r = i * 32 + (tid >> 3);
        int c4 = (tid & 7) * 4;
        int grow = row0 + r;
        if (grow > nrows - 1) grow = nrows - 1;
        float4 v = *(const float4*)&A[(size_t)grow * K + k0 + c4];
        if constexpr (LN) {
          float m = mu_s[r], s = rs_s[r];
          float4 g = *(const float4*)&gamma[k0 + c4];
          float4 b = *(const float4*)&beta[k0 + c4];
          v.x = (v.x - m) * s * g.x + b.x;
          v.y = (v.y - m) * s * g.y + b.y;
          v.z = (v.z - m) * s * g.z + b.z;
          v.w = (v.w - m) * s * g.w + b.w;
        }
        float vv[4] = {v.x, v.y, v.z, v.w};
#pragma unroll
        for (int j = 0; j < 4; ++j) {
          __bf16 h = (__bf16)vv[j];
          __bf16 l = (__bf16)(vv[j] - (float)h);
          As_hi[r * BKP + c4 + j] = __builtin_bit_cast(unsigned short, h);
          As_lo[r * BKP + c4 + j] = __builtin_bit_cast(unsigned short, l);
        }
      }
    } else {
      const half_t* A = (const half_t*)Avoid;
      int r = tid >> 2;
      int c8 = (tid & 3) * 8;
      int grow = row0 + r;
      if (grow > nrows - 1) grow = nrows - 1;
      half8_t v = *(const half8_t*)&A[(size_t)grow * K + k0 + c8];
#pragma unroll
      for (int j = 0; j < 8; ++j) {
        float f = (float)v[j];
        __bf16 h = (__bf16)f;
        __bf16 l = (__bf16)(f - (float)h);
        As_hi[r * BKP + c8 + j] = __builtin_bit_cast(unsigned short, h);
        As_lo[r * BKP + c8 + j] = __builtin_bit_cast(unsigned short, l);
      }
    }
#pragma unroll
    for (int i = 0; i < NOUT / 64; ++i) {
      int n = i * 64 + (tid >> 2);
      int c8 = (tid & 3) * 8;
      *(uint4*)&Bs_hi[n * BKP + c8] = *(const uint4*)&Wt_hi[(size_t)n * K + k0 + c8];
      *(uint4*)&Bs_lo[n * BKP + c8] = *(const uint4*)&Wt_lo[(size_t)n * K + k0 + c8];
    }
    __syncthreads();

    bf16x8 ah = *(const bf16x8*)&As_hi[(w * 16 + l16) * BKP + quad * 8];
    bf16x8 al = *(const bf16x8*)&As_lo[(w * 16 + l16) * BKP + quad * 8];
#pragma unroll
    for (int t = 0; t < NT; ++t) {
      bf16x8 bh = *(const bf16x8*)&Bs_hi[(t * 16 + l16) * BKP + quad * 8];
      bf16x8 bl = *(const bf16x8*)&Bs_lo[(t * 16 + l16) * BKP + quad * 8];
      acc[t] = __builtin_amdgcn_mfma_f32_16x16x32_bf16(ah, bh, acc[t], 0, 0, 0);
      acc[t] = __builtin_amdgcn_mfma_f32_16x16x32_bf16(al, bh, acc[t], 0, 0, 0);
      acc[t] = __builtin_amdgcn_mfma_f32_16x16x32_bf16(ah, bl, acc[t], 0, 0, 0);
    }
    __syncthreads();
  }

#pragma unroll
  for (int t = 0; t < NT; ++t) {
#pragma unroll
    for (int r = 0; r < 4; ++r) {
      int grow = row0 + w * 16 + quad * 4 + r;
      if (grow < nrows) out[(size_t)grow * NOUT + t * 16 + l16] = (half_t)acc[t][r];
    }
  }
}

// ---------------- fused launches -------------------------------------------
// smem: max(scatter 20480, gemm<256,128> 31232) = 31232
__global__ __launch_bounds__(256) void fused_scatter_gemm1(
    const int* __restrict__ src, const int* __restrict__ dst,
    int* __restrict__ bcur, unsigned int* __restrict__ binned, int E,
    const float* __restrict__ x,
    const unsigned short* __restrict__ W1t_hi, const unsigned short* __restrict__ W1t_lo,
    const float* __restrict__ gamma, const float* __restrict__ beta,
    half_t* __restrict__ t, int nrows, int nscat) {
  __shared__ __align__(16) char smem[31232];
  if ((int)blockIdx.x < nscat)
    scatter_body(smem, blockIdx.x, src, dst, bcur, binned, E);
  else
    gemm_body<256, 128, true, false>(smem, blockIdx.x - nscat, x, W1t_hi, W1t_lo,
                                     gamma, beta, t, nrows);
}

// smem: max(sort 36864, gemm 31232) = 36864
__global__ __launch_bounds__(256) void fused_sort_gemm1(
    const unsigned int* __restrict__ binned, const int* __restrict__ bbase,
    int* __restrict__ srcs, int* __restrict__ offs, float* __restrict__ dinv,
    int N, int NB, int E,
    const float* __restrict__ x,
    const unsigned short* __restrict__ W1t_hi, const unsigned short* __restrict__ W1t_lo,
    const float* __restrict__ gamma, const float* __restrict__ beta,
    half_t* __restrict__ t, int nrows, int g1a) {
  __shared__ __align__(16) char smem[36864];
  if ((int)blockIdx.x < NB)
    sort_body(smem, blockIdx.x, binned, bbase, srcs, offs, dinv, N, NB, E);
  else
    gemm_body<256, 128, true, false>(smem, g1a + (blockIdx.x - NB), x, W1t_hi, W1t_lo,
                                     gamma, beta, t, nrows);
}

// ---------------- standalone GEMM for layers 2/3 ---------------------------
template <int K, int NOUT>
__launch_bounds__(256)
__global__ void gemm_k(const half_t* __restrict__ A,
                       const unsigned short* __restrict__ Wt_hi,
                       const unsigned short* __restrict__ Wt_lo,
                       half_t* __restrict__ out, int nrows) {
  constexpr int SM = 64 * 40 * 4 + NOUT * 40 * 4 + 512;
  __shared__ __align__(16) char smem[SM];
  gemm_body<K, NOUT, false, true>(smem, blockIdx.x, A, Wt_hi, Wt_lo,
                                  nullptr, nullptr, out, nrows);
}

// ---------------- aggregation: quarter-wave gathers, srcs + dinv[src] ------
__global__ __launch_bounds__(256) void agg128_h(const half_t* __restrict__ t,
                                                const int* __restrict__ offs,
                                                const int* __restrict__ srcs,
                                                const float* __restrict__ dinv,
                                                const float* __restrict__ bias,
                                                half_t* __restrict__ out, int n) {
  int gid = blockIdx.x * blockDim.x + threadIdx.x;
  int node = gid >> 6, lane = gid & 63;
  if (node >= n) return;
  int qw = lane >> 4;
  int fl = lane & 15;
  int e0 = offs[node], e1 = offs[node + 1];
  float acc[8] = {0.f, 0.f, 0.f, 0.f, 0.f, 0.f, 0.f, 0.f};
  int e = e0 + qw;
  for (; e + 12 < e1; e += 16) {
    int sa = srcs[e], sb = srcs[e + 4], sc = srcs[e + 8], sd = srcs[e + 12];
    float wa = dinv[sa], wb = dinv[sb], wc = dinv[sc], wd = dinv[sd];
    half8_t va = *(const half8_t*)(t + ((size_t)sa << 7) + fl * 8);
    half8_t vb = *(const half8_t*)(t + ((size_t)sb << 7) + fl * 8);
    half8_t vc = *(const half8_t*)(t + ((size_t)sc << 7) + fl * 8);
    half8_t vd = *(const half8_t*)(t + ((size_t)sd << 7) + fl * 8);
#pragma unroll
    for (int j = 0; j < 8; ++j) {
      acc[j] = fmaf(wa, (float)va[j], acc[j]);
      acc[j] = fmaf(wb, (float)vb[j], acc[j]);
      acc[j] = fmaf(wc, (float)vc[j], acc[j]);
      acc[j] = fmaf(wd, (float)vd[j], acc[j]);
    }
  }
  for (; e < e1; e += 4) {
    int s = srcs[e];
    float w = dinv[s];
    half8_t v = *(const half8_t*)(t + ((size_t)s << 7) + fl * 8);
#pragma unroll
    for (int j = 0; j < 8; ++j) acc[j] = fmaf(w, (float)v[j], acc[j]);
  }
#pragma unroll
  for (int j = 0; j < 8; ++j) {
    acc[j] += __shfl_xor(acc[j], 16);
    acc[j] += __shfl_xor(acc[j], 32);
  }
  if (qw == 0) {
    float di = dinv[node];
    float dii = di * di;
    half8_t sv = *(const half8_t*)(t + ((size_t)node << 7) + fl * 8);
    float4 b0 = *(const float4*)(bias + fl * 8);
    float4 b1 = *(const float4*)(bias + fl * 8 + 4);
    float bb[8] = {b0.x, b0.y, b0.z, b0.w, b1.x, b1.y, b1.z, b1.w};
    half8_t o;
#pragma unroll
    for (int j = 0; j < 8; ++j) {
      float v = di * acc[j] + dii * (float)sv[j] + bb[j];
      o[j] = (half_t)fmaxf(v, 0.f);
    }
    *(half8_t*)(out + ((size_t)node << 7) + fl * 8) = o;
  }
}

__global__ __launch_bounds__(256) void agg64_h(const half_t* __restrict__ t,
                                               const int* __restrict__ offs,
                                               const int* __restrict__ srcs,
                                               const float* __restrict__ dinv,
                                               const float* __restrict__ bias,
                                               float* __restrict__ out, int n) {
  int gid = blockIdx.x * blockDim.x + threadIdx.x;
  int node = gid >> 6, lane = gid & 63;
  if (node >= n) return;
  int og = lane >> 3;
  int fl = lane & 7;
  int e0 = offs[node], e1 = offs[node + 1];
  float acc[8] = {0.f, 0.f, 0.f, 0.f, 0.f, 0.f, 0.f, 0.f};
  int e = e0 + og;
  for (; e + 8 < e1; e += 16) {
    int sa = srcs[e], sb = srcs[e + 8];
    float wa = dinv[sa], wb = dinv[sb];
    half8_t va = *(const half8_t*)(t + ((size_t)sa << 6) + fl * 8);
    half8_t vb = *(const half8_t*)(t + ((size_t)sb << 6) + fl * 8);
#pragma unroll
    for (int j = 0; j < 8; ++j) {
      acc[j] = fmaf(wa, (float)va[j], acc[j]);
      acc[j] = fmaf(wb, (float)vb[j], acc[j]);
    }
  }
  for (; e < e1; e += 8) {
    int s = srcs[e];
    float w = dinv[s];
    half8_t v = *(const half8_t*)(t + ((size_t)s << 6) + fl * 8);
#pragma unroll
    for (int j = 0; j < 8; ++j) acc[j] = fmaf(w, (float)v[j], acc[j]);
  }
#pragma unroll
  for (int j = 0; j < 8; ++j) {
    acc[j] += __shfl_xor(acc[j], 8);
    acc[j] += __shfl_xor(acc[j], 16);
    acc[j] += __shfl_xor(acc[j], 32);
  }
  if (og == 0) {
    float di = dinv[node];
    float dii = di * di;
    half8_t sv = *(const half8_t*)(t + ((size_t)node << 6) + fl * 8);
    float4 b0 = *(const float4*)(bias + fl * 8);
    float4 b1 = *(const float4*)(bias + fl * 8 + 4);
    float bb[8] = {b0.x, b0.y, b0.z, b0.w, b1.x, b1.y, b1.z, b1.w};
    float ov[8];
#pragma unroll
    for (int j = 0; j < 8; ++j) ov[j] = di * acc[j] + dii * (float)sv[j] + bb[j];
    *(float4*)(out + ((size_t)node << 6) + fl * 8) = make_float4(ov[0], ov[1], ov[2], ov[3]);
    *(float4*)(out + ((size_t)node << 6) + fl * 8 + 4) = make_float4(ov[4], ov[5], ov[6], ov[7]);
  }
}

extern "C" void kernel_launch(void* const* d_in, const int* in_sizes, int n_in,
                              void* d_out, int out_size, void* d_ws, size_t ws_size,
                              hipStream_t stream) {
  const float* x = (const float*)d_in[0];
  const int* ei = (const int*)d_in[1];
  const float* gamma = (const float*)d_in[2];
  const float* beta = (const float*)d_in[3];
  const float* W1 = (const float*)d_in[4];
  const float* b1 = (const float*)d_in[5];
  const float* W2 = (const float*)d_in[6];
  const float* b2 = (const float*)d_in[7];
  const float* W3 = (const float*)d_in[8];
  const float* b3 = (const float*)d_in[9];
  float* out = (float*)d_out;

  const int N = in_sizes[0] / 256;  // 50000 < 65536: packed records valid
  const int E = in_sizes[1] / 2;
  const int* src = ei;
  const int* dst = ei + E;
  const int NB = (N + 255) >> 8;

  char* ws = (char*)d_ws;
  auto alloc = [&](size_t bytes) -> char* {
    char* p = ws;
    ws += (bytes + 255) & ~(size_t)255;
    return p;
  };
  int* bcnt_multi = (int*)alloc(NHIST * 256 * 4);
  int* bbase = (int*)alloc(257 * 4);
  int* bcur = (int*)alloc(256 * 4);
  unsigned int* binned = (unsigned int*)alloc((size_t)E * 4);
  int* srcs = (int*)alloc((size_t)E * 4);
  int* offs = (int*)alloc((size_t)(N + 1) * 4);
  float* dinv = (float*)alloc((size_t)N * 4);
  half_t* t = (half_t*)alloc((size_t)N * 128 * 2);
  half_t* h = (half_t*)alloc((size_t)N * 128 * 2);
  unsigned short* W1t_hi = (unsigned short*)alloc(256 * 128 * 2);
  unsigned short* W1t_lo = (unsigned short*)alloc(256 * 128 * 2);
  unsigned short* W2t_hi = (unsigned short*)alloc(128 * 128 * 2);
  unsigned short* W2t_lo = (unsigned short*)alloc(128 * 128 * 2);
  unsigned short* W3t_hi = (unsigned short*)alloc(128 * 64 * 2);
  unsigned short* W3t_lo = (unsigned short*)alloc(128 * 64 * 2);

  // ---- prep: hist x256 + wsplit x3 in one launch ----
  prep_misc<<<NHIST + 224, 256, 0, stream>>>(
      dst, W1, W2, W3, bcnt_multi, W1t_hi, W1t_lo, W2t_hi, W2t_lo,
      W3t_hi, W3t_lo, E);

  // ---- scan ----
  scan_buckets<<<1, 256, 0, stream>>>(bcnt_multi, bbase, bcur, NB, E);

  const int gemm_blocks = (N + 63) / 64;
  const int G1A = gemm_blocks / 2;
  const int G1B = gemm_blocks - G1A;
  const int NSCAT = (E + CHUNK - 1) / CHUNK;
  const int agg_blocks = (N + 3) / 4;

  // ---- CSR scatter ∥ GEMM1 (first half) ----
  fused_scatter_gemm1<<<NSCAT + G1A, 256, 0, stream>>>(
      src, dst, bcur, binned, E, x, W1t_hi, W1t_lo, gamma, beta, t, N, NSCAT);

  // ---- CSR sort ∥ GEMM1 (second half) ----
  fused_sort_gemm1<<<NB + G1B, 256, 0, stream>>>(
      binned, bbase, srcs, offs, dinv, N, NB, E, x, W1t_hi, W1t_lo, gamma, beta,
      t, N, G1A);

  // ---- layer 1 aggregation ----
  agg128_h<<<agg_blocks, 256, 0, stream>>>(t, offs, srcs, dinv, b1, h, N);

  // ---- layer 2 ----
  gemm_k<128, 128><<<gemm_blocks, 256, 0, stream>>>(h, W2t_hi, W2t_lo, t, N);
  agg128_h<<<agg_blocks, 256, 0, stream>>>(t, offs, srcs, dinv, b2, h, N);

  // ---- layer 3 ----
  gemm_k<128, 64><<<gemm_blocks, 256, 0, stream>>>(h, W3t_hi, W3t_lo, t, N);
  agg64_h<<<agg_blocks, 256, 0, stream>>>(t, offs, srcs, dinv, b3, out, N);
}

// Round 6
// 268.723 us; speedup vs baseline: 1.0495x; 1.0102x over previous
//
#include <hip/hip_runtime.h>
#include <cstdint>
#include <cstddef>

// ---------------------------------------------------------------------------
// GCN encoder: z = GCN3( relu(GCN2( relu(GCN1( LN(x) )) )) )
// R17: GEMM restructure from R15/R16 counter evidence (grid starvation at
//      BM=64: 782 blocks = 3/CU; fp16 input needlessly converted to bf16):
//  A) BM=32 (1563 blocks = 6.1/CU). 4 waves = 2 row-groups x 2 col-groups;
//     fragment/MFMA layout per wave unchanged.
//  B) Layers 2/3 use mfma_f32_16x16x32_f16: A staged as raw fp16 (8B copies,
//     zero conversion VALU), W as fp16-hi + fp16-lo*2048 (denorm-safe),
//     2 MFMAs into acc1/acc2, epilogue acc1 + acc2/2048. Error improves vs
//     bf16 triple. Layer 1 keeps bf16-triple (fp32+LN input).
//  CSR build, fusion structure, aggs unchanged from R16 (271.5 us).
// ---------------------------------------------------------------------------

typedef __attribute__((ext_vector_type(8))) __bf16 bf16x8;
typedef __attribute__((ext_vector_type(4))) float f32x4;
typedef _Float16 half_t;
typedef __attribute__((ext_vector_type(8))) _Float16 half8_t;

#define NHIST 256
#define CHUNK 4096
#define MAXB 8192

// ---------------- prep: hist x256 | wsplit x3, by block range --------------
__global__ __launch_bounds__(256) void prep_misc(
    const int* __restrict__ dst,
    const float* __restrict__ W1, const float* __restrict__ W2,
    const float* __restrict__ W3,
    int* __restrict__ bcnt_multi,
    unsigned short* __restrict__ W1t_hi, unsigned short* __restrict__ W1t_lo,
    unsigned short* __restrict__ W2t_hi, unsigned short* __restrict__ W2t_lo,
    unsigned short* __restrict__ W3t_hi, unsigned short* __restrict__ W3t_lo,
    int E) {
  int blk = blockIdx.x;
  int tid = threadIdx.x;
  if (blk < NHIST) {
    __shared__ int h[256];
    h[tid] = 0;
    __syncthreads();
    for (int e = blk * 256 + tid; e < E; e += NHIST * 256)
      atomicAdd(&h[dst[e] >> 8], 1);
    __syncthreads();
    bcnt_multi[blk * 256 + tid] = h[tid];
    return;
  }
  int idx = (blk - NHIST) * 256 + tid;
  if (idx < 32768) {
    // W1: bf16 hi/lo (layer-1 bf16-triple path)
    int k = idx / 128, c = idx % 128;
    float v = W1[idx];
    __bf16 h = (__bf16)v;
    __bf16 l = (__bf16)(v - (float)h);
    W1t_hi[(size_t)c * 256 + k] = __builtin_bit_cast(unsigned short, h);
    W1t_lo[(size_t)c * 256 + k] = __builtin_bit_cast(unsigned short, l);
    return;
  }
  // W2/W3: fp16 hi + fp16 lo*2048 (layer-2/3 f16 dual-MFMA path)
  const float* W;
  unsigned short *Th, *Tl;
  int K, NOUT;
  if (idx < 49152) {
    idx -= 32768;
    W = W2; Th = W2t_hi; Tl = W2t_lo; K = 128; NOUT = 128;
  } else {
    idx -= 49152;
    W = W3; Th = W3t_hi; Tl = W3t_lo; K = 128; NOUT = 64;
  }
  int k = idx / NOUT, c = idx % NOUT;
  float v = W[idx];
  half_t h = (half_t)v;
  half_t l = (half_t)((v - (float)h) * 2048.0f);
  Th[(size_t)c * K + k] = __builtin_bit_cast(unsigned short, h);
  Tl[(size_t)c * K + k] = __builtin_bit_cast(unsigned short, l);
}

// ---------------- scan: sum 256 slices, exclusive prefix ----------------
__global__ __launch_bounds__(256) void scan_buckets(const int* __restrict__ bcnt_multi,
                                                    int* __restrict__ bbase,
                                                    int* __restrict__ bcur, int NB, int E) {
  __shared__ int tmp[256];
  int t = threadIdx.x;
  int v = 0;
  for (int h = 0; h < NHIST; ++h) v += bcnt_multi[h * 256 + t];
  tmp[t] = v;
  __syncthreads();
  for (int off = 1; off < 256; off <<= 1) {
    int x = (t >= off) ? tmp[t - off] : 0;
    __syncthreads();
    tmp[t] += x;
    __syncthreads();
  }
  int excl = tmp[t] - v;
  if (t < NB) { bbase[t] = excl; bcur[t] = excl; }
  if (t == 0) bbase[NB] = E;
}

// ---------------- scatter body (smem: 20480 B) ----------------
// record = (dst << 16) | src  (both < 65536)
__device__ __forceinline__ void scatter_body(char* smem_raw, int bid,
                                             const int* __restrict__ src,
                                             const int* __restrict__ dst,
                                             int* __restrict__ bcur,
                                             unsigned int* __restrict__ binned, int E) {
  unsigned int* recs = (unsigned int*)smem_raw;          // 16384 B
  int* hist = (int*)(smem_raw + 16384);
  int* lbase = hist + 256;
  int* resv = lbase + 256;
  int* cur = resv + 256;
  int t = threadIdx.x;
  int e0 = bid * CHUNK;
  if (e0 >= E) return;
  int len = min(CHUNK, E - e0);
  hist[t] = 0;
  cur[t] = 0;
  __syncthreads();
  for (int i = t; i < len; i += 256) atomicAdd(&hist[dst[e0 + i] >> 8], 1);
  __syncthreads();
  int v = hist[t];
  lbase[t] = v;
  __syncthreads();
  for (int off = 1; off < 256; off <<= 1) {
    int x = (t >= off) ? lbase[t - off] : 0;
    __syncthreads();
    lbase[t] += x;
    __syncthreads();
  }
  int myexcl = lbase[t] - v;
  if (v) resv[t] = atomicAdd(&bcur[t], v);
  __syncthreads();
  lbase[t] = myexcl;
  __syncthreads();
  for (int i = t; i < len; i += 256) {
    int d = dst[e0 + i], s = src[e0 + i];
    int b = d >> 8;
    int r = atomicAdd(&cur[b], 1);
    recs[lbase[b] + r] = ((unsigned int)d << 16) | (unsigned int)s;
  }
  __syncthreads();
  for (int i = t; i < len; i += 256) {
    unsigned int rc = recs[i];
    int b = rc >> 24;
    binned[resv[b] + (i - lbase[b])] = rc;
  }
}

// ---------------- sort body (smem: 36864 B) ----------------
__device__ __forceinline__ void sort_body(char* smem_raw, int b,
                                          const unsigned int* __restrict__ binned,
                                          const int* __restrict__ bbase,
                                          int* __restrict__ srcs,
                                          int* __restrict__ offs,
                                          float* __restrict__ dinv,
                                          int N, int NB, int E) {
  int* sstage = (int*)smem_raw;                           // 32768 B
  int* hist = (int*)(smem_raw + 32768);
  int* nbase = hist + 256;
  int* cur = nbase + 256;
  int* tmp = cur + 256;
  int t = threadIdx.x;
  int base = bbase[b], end = bbase[b + 1];
  int L = end - base;
  if (L > MAXB) L = MAXB;
  hist[t] = 0;
  __syncthreads();
  for (int i = t; i < L; i += 256)
    atomicAdd(&hist[(binned[base + i] >> 16) & 255], 1);
  __syncthreads();
  int v = hist[t];
  tmp[t] = v;
  __syncthreads();
  for (int off = 1; off < 256; off <<= 1) {
    int x = (t >= off) ? tmp[t - off] : 0;
    __syncthreads();
    tmp[t] += x;
    __syncthreads();
  }
  int excl = tmp[t] - v;
  nbase[t] = excl;
  cur[t] = excl;
  int node = (b << 8) + t;
  if (node < N) {
    offs[node] = base + excl;
    dinv[node] = rsqrtf(1.0f + (float)v);
  }
  if (b == NB - 1 && t == 0) offs[N] = E;
  __syncthreads();
  for (int i = t; i < L; i += 256) {
    unsigned int p = binned[base + i];
    int ld = (p >> 16) & 255;
    int slot = atomicAdd(&cur[ld], 1);
    sstage[slot] = (int)(p & 0xFFFFu);
  }
  __syncthreads();
  for (int i = t; i < L; i += 256) srcs[base + i] = sstage[i];
}

// ---------------- GEMM body: BM=32, 2x2 wave split, padded LDS -------------
// A_FP16=false: fp32 input (+opt LN), bf16 hi/lo triple-MFMA, 1 acc.
// A_FP16=true:  fp16 input staged raw, f16 dual-MFMA (W hi + lo*2048), 2 acc.
template <int K, int NOUT, bool LN, bool A_FP16>
__device__ __forceinline__ void gemm_body(char* smem_raw, int gbid,
                                          const void* __restrict__ Avoid,
                                          const unsigned short* __restrict__ Wt_hi,
                                          const unsigned short* __restrict__ Wt_lo,
                                          const float* __restrict__ gamma,
                                          const float* __restrict__ beta,
                                          half_t* __restrict__ out, int nrows) {
  constexpr int BM = 32, BK = 32, BKP = BK + 8;
  constexpr int NTW = NOUT / 32;  // col tiles per wave (half of NOUT / 16)

  const int tid = threadIdx.x;
  const int lane = tid & 63;
  const int w = tid >> 6;
  const int quad = lane >> 4;
  const int l16 = lane & 15;
  const int rg = (w & 1) * 16;            // wave row-group
  const int cg = (w >> 1) * (NOUT / 2);   // wave col-group
  const int row0 = gbid * BM;

  if constexpr (!A_FP16) {
    unsigned short* As_hi = (unsigned short*)smem_raw;        // BM*BKP
    unsigned short* As_lo = As_hi + BM * BKP;
    unsigned short* Bs_hi = As_lo + BM * BKP;                 // NOUT*BKP
    unsigned short* Bs_lo = Bs_hi + NOUT * BKP;
    float* mu_s = (float*)(Bs_lo + NOUT * BKP);
    float* rs_s = mu_s + BM;
    const float* A = (const float*)Avoid;

    if constexpr (LN) {
      // per-row LN stats: 8 threads/row, K/32 float4 each, 3-step shfl.
      int r = tid >> 3;
      int part = tid & 7;
      int grow = row0 + r;
      if (grow > nrows - 1) grow = nrows - 1;
      const float4* rp = (const float4*)(A + (size_t)grow * K);
      float s = 0.f, s2 = 0.f;
#pragma unroll
      for (int j = 0; j < K / 32; ++j) {
        float4 v = rp[part * (K / 32) + j];
        s += v.x + v.y + v.z + v.w;
        s2 += v.x * v.x + v.y * v.y + v.z * v.z + v.w * v.w;
      }
      s += __shfl_xor(s, 1);
      s += __shfl_xor(s, 2);
      s += __shfl_xor(s, 4);
      s2 += __shfl_xor(s2, 1);
      s2 += __shfl_xor(s2, 2);
      s2 += __shfl_xor(s2, 4);
      if (part == 0) {
        float m = s * (1.0f / (float)K);
        float var = s2 * (1.0f / (float)K) - m * m;
        mu_s[r] = m;
        rs_s[r] = rsqrtf(var + 1e-5f);
      }
      __syncthreads();
    }

    f32x4 acc[NTW];
#pragma unroll
    for (int t = 0; t < NTW; ++t) acc[t] = (f32x4){0.f, 0.f, 0.f, 0.f};

    for (int k0 = 0; k0 < K; k0 += BK) {
      {
        int r = tid >> 3;
        int c4 = (tid & 7) * 4;
        int grow = row0 + r;
        if (grow > nrows - 1) grow = nrows - 1;
        float4 v = *(const float4*)&A[(size_t)grow * K + k0 + c4];
        if constexpr (LN) {
          float m = mu_s[r], s = rs_s[r];
          float4 g = *(const float4*)&gamma[k0 + c4];
          float4 b = *(const float4*)&beta[k0 + c4];
          v.x = (v.x - m) * s * g.x + b.x;
          v.y = (v.y - m) * s * g.y + b.y;
          v.z = (v.z - m) * s * g.z + b.z;
          v.w = (v.w - m) * s * g.w + b.w;
        }
        float vv[4] = {v.x, v.y, v.z, v.w};
#pragma unroll
        for (int j = 0; j < 4; ++j) {
          __bf16 h = (__bf16)vv[j];
          __bf16 l = (__bf16)(vv[j] - (float)h);
          As_hi[r * BKP + c4 + j] = __builtin_bit_cast(unsigned short, h);
          As_lo[r * BKP + c4 + j] = __builtin_bit_cast(unsigned short, l);
        }
      }
#pragma unroll
      for (int i = 0; i < NOUT / 64; ++i) {
        int n = i * 64 + (tid >> 2);
        int c8 = (tid & 3) * 8;
        *(uint4*)&Bs_hi[n * BKP + c8] = *(const uint4*)&Wt_hi[(size_t)n * K + k0 + c8];
        *(uint4*)&Bs_lo[n * BKP + c8] = *(const uint4*)&Wt_lo[(size_t)n * K + k0 + c8];
      }
      __syncthreads();

      bf16x8 ah = *(const bf16x8*)&As_hi[(rg + l16) * BKP + quad * 8];
      bf16x8 al = *(const bf16x8*)&As_lo[(rg + l16) * BKP + quad * 8];
#pragma unroll
      for (int t = 0; t < NTW; ++t) {
        bf16x8 bh = *(const bf16x8*)&Bs_hi[(cg + t * 16 + l16) * BKP + quad * 8];
        bf16x8 bl = *(const bf16x8*)&Bs_lo[(cg + t * 16 + l16) * BKP + quad * 8];
        acc[t] = __builtin_amdgcn_mfma_f32_16x16x32_bf16(ah, bh, acc[t], 0, 0, 0);
        acc[t] = __builtin_amdgcn_mfma_f32_16x16x32_bf16(al, bh, acc[t], 0, 0, 0);
        acc[t] = __builtin_amdgcn_mfma_f32_16x16x32_bf16(ah, bl, acc[t], 0, 0, 0);
      }
      __syncthreads();
    }

#pragma unroll
    for (int t = 0; t < NTW; ++t) {
#pragma unroll
      for (int r = 0; r < 4; ++r) {
        int grow = row0 + rg + quad * 4 + r;
        if (grow < nrows)
          out[(size_t)grow * NOUT + cg + t * 16 + l16] = (half_t)acc[t][r];
      }
    }
  } else {
    half_t* As = (half_t*)smem_raw;                         // BM*BKP halves
    half_t* Bs_hi = As + BM * BKP;                          // NOUT*BKP
    half_t* Bs_lo = Bs_hi + NOUT * BKP;
    const half_t* A = (const half_t*)Avoid;

    f32x4 acc1[NTW], acc2[NTW];
#pragma unroll
    for (int t = 0; t < NTW; ++t) {
      acc1[t] = (f32x4){0.f, 0.f, 0.f, 0.f};
      acc2[t] = (f32x4){0.f, 0.f, 0.f, 0.f};
    }

    for (int k0 = 0; k0 < K; k0 += BK) {
      {
        int r = tid >> 3;
        int c4 = (tid & 7) * 4;
        int grow = row0 + r;
        if (grow > nrows - 1) grow = nrows - 1;
        *(uint2*)&As[r * BKP + c4] = *(const uint2*)&A[(size_t)grow * K + k0 + c4];
      }
#pragma unroll
      for (int i = 0; i < NOUT / 64; ++i) {
        int n = i * 64 + (tid >> 2);
        int c8 = (tid & 3) * 8;
        *(uint4*)&Bs_hi[n * BKP + c8] =
            *(const uint4*)&Wt_hi[(size_t)n * K + k0 + c8];
        *(uint4*)&Bs_lo[n * BKP + c8] =
            *(const uint4*)&Wt_lo[(size_t)n * K + k0 + c8];
      }
      __syncthreads();

      half8_t av = *(const half8_t*)&As[(rg + l16) * BKP + quad * 8];
#pragma unroll
      for (int t = 0; t < NTW; ++t) {
        half8_t bh = *(const half8_t*)&Bs_hi[(cg + t * 16 + l16) * BKP + quad * 8];
        half8_t bl = *(const half8_t*)&Bs_lo[(cg + t * 16 + l16) * BKP + quad * 8];
        acc1[t] = __builtin_amdgcn_mfma_f32_16x16x32_f16(av, bh, acc1[t], 0, 0, 0);
        acc2[t] = __builtin_amdgcn_mfma_f32_16x16x32_f16(av, bl, acc2[t], 0, 0, 0);
      }
      __syncthreads();
    }

#pragma unroll
    for (int t = 0; t < NTW; ++t) {
#pragma unroll
      for (int r = 0; r < 4; ++r) {
        int grow = row0 + rg + quad * 4 + r;
        if (grow < nrows)
          out[(size_t)grow * NOUT + cg + t * 16 + l16] =
              (half_t)(acc1[t][r] + acc2[t][r] * (1.0f / 2048.0f));
      }
    }
  }
}

// smem sizes
constexpr int GEMM1_SMEM = 32 * 40 * 4 + 128 * 40 * 4 + 256;  // 25856
// fused launches
__global__ __launch_bounds__(256) void fused_scatter_gemm1(
    const int* __restrict__ src, const int* __restrict__ dst,
    int* __restrict__ bcur, unsigned int* __restrict__ binned, int E,
    const float* __restrict__ x,
    const unsigned short* __restrict__ W1t_hi, const unsigned short* __restrict__ W1t_lo,
    const float* __restrict__ gamma, const float* __restrict__ beta,
    half_t* __restrict__ t, int nrows, int nscat) {
  __shared__ __align__(16) char smem[GEMM1_SMEM];  // > scatter's 20480
  if ((int)blockIdx.x < nscat)
    scatter_body(smem, blockIdx.x, src, dst, bcur, binned, E);
  else
    gemm_body<256, 128, true, false>(smem, blockIdx.x - nscat, x, W1t_hi, W1t_lo,
                                     gamma, beta, t, nrows);
}

__global__ __launch_bounds__(256) void fused_sort_gemm1(
    const unsigned int* __restrict__ binned, const int* __restrict__ bbase,
    int* __restrict__ srcs, int* __restrict__ offs, float* __restrict__ dinv,
    int N, int NB, int E,
    const float* __restrict__ x,
    const unsigned short* __restrict__ W1t_hi, const unsigned short* __restrict__ W1t_lo,
    const float* __restrict__ gamma, const float* __restrict__ beta,
    half_t* __restrict__ t, int nrows, int g1a) {
  __shared__ __align__(16) char smem[36864];  // sort 36864 > gemm 25856
  if ((int)blockIdx.x < NB)
    sort_body(smem, blockIdx.x, binned, bbase, srcs, offs, dinv, N, NB, E);
  else
    gemm_body<256, 128, true, false>(smem, g1a + (blockIdx.x - NB), x, W1t_hi, W1t_lo,
                                     gamma, beta, t, nrows);
}

// ---------------- standalone GEMM for layers 2/3 (f16 path) ----------------
template <int K, int NOUT>
__launch_bounds__(256)
__global__ void gemm_k(const half_t* __restrict__ A,
                       const unsigned short* __restrict__ Wt_hi,
                       const unsigned short* __restrict__ Wt_lo,
                       half_t* __restrict__ out, int nrows) {
  constexpr int SM = 32 * 40 * 2 + NOUT * 40 * 4;
  __shared__ __align__(16) char smem[SM];
  gemm_body<K, NOUT, false, true>(smem, blockIdx.x, A, Wt_hi, Wt_lo,
                                  nullptr, nullptr, out, nrows);
}

// ---------------- aggregation: quarter-wave gathers, srcs + dinv[src] ------
__global__ __launch_bounds__(256) void agg128_h(const half_t* __restrict__ t,
                                                const int* __restrict__ offs,
                                                const int* __restrict__ srcs,
                                                const float* __restrict__ dinv,
                                                const float* __restrict__ bias,
                                                half_t* __restrict__ out, int n) {
  int gid = blockIdx.x * blockDim.x + threadIdx.x;
  int node = gid >> 6, lane = gid & 63;
  if (node >= n) return;
  int qw = lane >> 4;
  int fl = lane & 15;
  int e0 = offs[node], e1 = offs[node + 1];
  float acc[8] = {0.f, 0.f, 0.f, 0.f, 0.f, 0.f, 0.f, 0.f};
  int e = e0 + qw;
  for (; e + 12 < e1; e += 16) {
    int sa = srcs[e], sb = srcs[e + 4], sc = srcs[e + 8], sd = srcs[e + 12];
    float wa = dinv[sa], wb = dinv[sb], wc = dinv[sc], wd = dinv[sd];
    half8_t va = *(const half8_t*)(t + ((size_t)sa << 7) + fl * 8);
    half8_t vb = *(const half8_t*)(t + ((size_t)sb << 7) + fl * 8);
    half8_t vc = *(const half8_t*)(t + ((size_t)sc << 7) + fl * 8);
    half8_t vd = *(const half8_t*)(t + ((size_t)sd << 7) + fl * 8);
#pragma unroll
    for (int j = 0; j < 8; ++j) {
      acc[j] = fmaf(wa, (float)va[j], acc[j]);
      acc[j] = fmaf(wb, (float)vb[j], acc[j]);
      acc[j] = fmaf(wc, (float)vc[j], acc[j]);
      acc[j] = fmaf(wd, (float)vd[j], acc[j]);
    }
  }
  for (; e < e1; e += 4) {
    int s = srcs[e];
    float w = dinv[s];
    half8_t v = *(const half8_t*)(t + ((size_t)s << 7) + fl * 8);
#pragma unroll
    for (int j = 0; j < 8; ++j) acc[j] = fmaf(w, (float)v[j], acc[j]);
  }
#pragma unroll
  for (int j = 0; j < 8; ++j) {
    acc[j] += __shfl_xor(acc[j], 16);
    acc[j] += __shfl_xor(acc[j], 32);
  }
  if (qw == 0) {
    float di = dinv[node];
    float dii = di * di;
    half8_t sv = *(const half8_t*)(t + ((size_t)node << 7) + fl * 8);
    float4 b0 = *(const float4*)(bias + fl * 8);
    float4 b1 = *(const float4*)(bias + fl * 8 + 4);
    float bb[8] = {b0.x, b0.y, b0.z, b0.w, b1.x, b1.y, b1.z, b1.w};
    half8_t o;
#pragma unroll
    for (int j = 0; j < 8; ++j) {
      float v = di * acc[j] + dii * (float)sv[j] + bb[j];
      o[j] = (half_t)fmaxf(v, 0.f);
    }
    *(half8_t*)(out + ((size_t)node << 7) + fl * 8) = o;
  }
}

__global__ __launch_bounds__(256) void agg64_h(const half_t* __restrict__ t,
                                               const int* __restrict__ offs,
                                               const int* __restrict__ srcs,
                                               const float* __restrict__ dinv,
                                               const float* __restrict__ bias,
                                               float* __restrict__ out, int n) {
  int gid = blockIdx.x * blockDim.x + threadIdx.x;
  int node = gid >> 6, lane = gid & 63;
  if (node >= n) return;
  int og = lane >> 3;
  int fl = lane & 7;
  int e0 = offs[node], e1 = offs[node + 1];
  float acc[8] = {0.f, 0.f, 0.f, 0.f, 0.f, 0.f, 0.f, 0.f};
  int e = e0 + og;
  for (; e + 8 < e1; e += 16) {
    int sa = srcs[e], sb = srcs[e + 8];
    float wa = dinv[sa], wb = dinv[sb];
    half8_t va = *(const half8_t*)(t + ((size_t)sa << 6) + fl * 8);
    half8_t vb = *(const half8_t*)(t + ((size_t)sb << 6) + fl * 8);
#pragma unroll
    for (int j = 0; j < 8; ++j) {
      acc[j] = fmaf(wa, (float)va[j], acc[j]);
      acc[j] = fmaf(wb, (float)vb[j], acc[j]);
    }
  }
  for (; e < e1; e += 8) {
    int s = srcs[e];
    float w = dinv[s];
    half8_t v = *(const half8_t*)(t + ((size_t)s << 6) + fl * 8);
#pragma unroll
    for (int j = 0; j < 8; ++j) acc[j] = fmaf(w, (float)v[j], acc[j]);
  }
#pragma unroll
  for (int j = 0; j < 8; ++j) {
    acc[j] += __shfl_xor(acc[j], 8);
    acc[j] += __shfl_xor(acc[j], 16);
    acc[j] += __shfl_xor(acc[j], 32);
  }
  if (og == 0) {
    float di = dinv[node];
    float dii = di * di;
    half8_t sv = *(const half8_t*)(t + ((size_t)node << 6) + fl * 8);
    float4 b0 = *(const float4*)(bias + fl * 8);
    float4 b1 = *(const float4*)(bias + fl * 8 + 4);
    float bb[8] = {b0.x, b0.y, b0.z, b0.w, b1.x, b1.y, b1.z, b1.w};
    float ov[8];
#pragma unroll
    for (int j = 0; j < 8; ++j) ov[j] = di * acc[j] + dii * (float)sv[j] + bb[j];
    *(float4*)(out + ((size_t)node << 6) + fl * 8) = make_float4(ov[0], ov[1], ov[2], ov[3]);
    *(float4*)(out + ((size_t)node << 6) + fl * 8 + 4) = make_float4(ov[4], ov[5], ov[6], ov[7]);
  }
}

extern "C" void kernel_launch(void* const* d_in, const int* in_sizes, int n_in,
                              void* d_out, int out_size, void* d_ws, size_t ws_size,
                              hipStream_t stream) {
  const float* x = (const float*)d_in[0];
  const int* ei = (const int*)d_in[1];
  const float* gamma = (const float*)d_in[2];
  const float* beta = (const float*)d_in[3];
  const float* W1 = (const float*)d_in[4];
  const float* b1 = (const float*)d_in[5];
  const float* W2 = (const float*)d_in[6];
  const float* b2 = (const float*)d_in[7];
  const float* W3 = (const float*)d_in[8];
  const float* b3 = (const float*)d_in[9];
  float* out = (float*)d_out;

  const int N = in_sizes[0] / 256;  // 50000 < 65536: packed records valid
  const int E = in_sizes[1] / 2;
  const int* src = ei;
  const int* dst = ei + E;
  const int NB = (N + 255) >> 8;

  char* ws = (char*)d_ws;
  auto alloc = [&](size_t bytes) -> char* {
    char* p = ws;
    ws += (bytes + 255) & ~(size_t)255;
    return p;
  };
  int* bcnt_multi = (int*)alloc(NHIST * 256 * 4);
  int* bbase = (int*)alloc(257 * 4);
  int* bcur = (int*)alloc(256 * 4);
  unsigned int* binned = (unsigned int*)alloc((size_t)E * 4);
  int* srcs = (int*)alloc((size_t)E * 4);
  int* offs = (int*)alloc((size_t)(N + 1) * 4);
  float* dinv = (float*)alloc((size_t)N * 4);
  half_t* t = (half_t*)alloc((size_t)N * 128 * 2);
  half_t* h = (half_t*)alloc((size_t)N * 128 * 2);
  unsigned short* W1t_hi = (unsigned short*)alloc(256 * 128 * 2);
  unsigned short* W1t_lo = (unsigned short*)alloc(256 * 128 * 2);
  unsigned short* W2t_hi = (unsigned short*)alloc(128 * 128 * 2);
  unsigned short* W2t_lo = (unsigned short*)alloc(128 * 128 * 2);
  unsigned short* W3t_hi = (unsigned short*)alloc(128 * 64 * 2);
  unsigned short* W3t_lo = (unsigned short*)alloc(128 * 64 * 2);

  // ---- prep: hist x256 + wsplit x3 in one launch ----
  prep_misc<<<NHIST + 224, 256, 0, stream>>>(
      dst, W1, W2, W3, bcnt_multi, W1t_hi, W1t_lo, W2t_hi, W2t_lo,
      W3t_hi, W3t_lo, E);

  // ---- scan ----
  scan_buckets<<<1, 256, 0, stream>>>(bcnt_multi, bbase, bcur, NB, E);

  const int gemm_blocks = (N + 31) / 32;  // BM=32
  const int G1A = gemm_blocks / 2;
  const int G1B = gemm_blocks - G1A;
  const int NSCAT = (E + CHUNK - 1) / CHUNK;
  const int agg_blocks = (N + 3) / 4;

  // ---- CSR scatter ∥ GEMM1 (first half) ----
  fused_scatter_gemm1<<<NSCAT + G1A, 256, 0, stream>>>(
      src, dst, bcur, binned, E, x, W1t_hi, W1t_lo, gamma, beta, t, N, NSCAT);

  // ---- CSR sort ∥ GEMM1 (second half) ----
  fused_sort_gemm1<<<NB + G1B, 256, 0, stream>>>(
      binned, bbase, srcs, offs, dinv, N, NB, E, x, W1t_hi, W1t_lo, gamma, beta,
      t, N, G1A);

  // ---- layer 1 aggregation ----
  agg128_h<<<agg_blocks, 256, 0, stream>>>(t, offs, srcs, dinv, b1, h, N);

  // ---- layer 2 ----
  gemm_k<128, 128><<<gemm_blocks, 256, 0, stream>>>(h, W2t_hi, W2t_lo, t, N);
  agg128_h<<<agg_blocks, 256, 0, stream>>>(t, offs, srcs, dinv, b2, h, N);

  // ---- layer 3 ----
  gemm_k<128, 64><<<gemm_blocks, 256, 0, stream>>>(h, W3t_hi, W3t_lo, t, N);
  agg64_h<<<agg_blocks, 256, 0, stream>>>(t, offs, srcs, dinv, b3, out, N);
}

// Round 7
// 256.279 us; speedup vs baseline: 1.1004x; 1.0486x over previous
//
#include <hip/hip_runtime.h>
#include <cstdint>
#include <cstddef>

// ---------------------------------------------------------------------------
// GCN encoder: z = GCN3( relu(GCN2( relu(GCN1( LN(x) )) )) )
// R18: agg->GEMM fusion for layers 2/3. Each agg_gemm block aggregates its
//      32 output rows (CSR gather + relu + bias + self-term) straight into
//      the fp16 A-tile in LDS (As[32][136], 16B pad), then runs the f16
//      dual-MFMA k-loop staging only W. Removes the h round-trips, 2
//      launches, and overlaps gather (mem) with MFMA (compute) across
//      co-resident blocks. 7 launches. Layer-1 CSR||GEMM1 fusion and final
//      agg64 unchanged from R17 (268.7 us).
// ---------------------------------------------------------------------------

typedef __attribute__((ext_vector_type(8))) __bf16 bf16x8;
typedef __attribute__((ext_vector_type(4))) float f32x4;
typedef _Float16 half_t;
typedef __attribute__((ext_vector_type(8))) _Float16 half8_t;

#define NHIST 256
#define CHUNK 4096
#define MAXB 8192

// ---------------- prep: hist x256 | wsplit x3, by block range --------------
__global__ __launch_bounds__(256) void prep_misc(
    const int* __restrict__ dst,
    const float* __restrict__ W1, const float* __restrict__ W2,
    const float* __restrict__ W3,
    int* __restrict__ bcnt_multi,
    unsigned short* __restrict__ W1t_hi, unsigned short* __restrict__ W1t_lo,
    unsigned short* __restrict__ W2t_hi, unsigned short* __restrict__ W2t_lo,
    unsigned short* __restrict__ W3t_hi, unsigned short* __restrict__ W3t_lo,
    int E) {
  int blk = blockIdx.x;
  int tid = threadIdx.x;
  if (blk < NHIST) {
    __shared__ int h[256];
    h[tid] = 0;
    __syncthreads();
    for (int e = blk * 256 + tid; e < E; e += NHIST * 256)
      atomicAdd(&h[dst[e] >> 8], 1);
    __syncthreads();
    bcnt_multi[blk * 256 + tid] = h[tid];
    return;
  }
  int idx = (blk - NHIST) * 256 + tid;
  if (idx < 32768) {
    // W1: bf16 hi/lo (layer-1 bf16-triple path)
    int k = idx / 128, c = idx % 128;
    float v = W1[idx];
    __bf16 h = (__bf16)v;
    __bf16 l = (__bf16)(v - (float)h);
    W1t_hi[(size_t)c * 256 + k] = __builtin_bit_cast(unsigned short, h);
    W1t_lo[(size_t)c * 256 + k] = __builtin_bit_cast(unsigned short, l);
    return;
  }
  // W2/W3: fp16 hi + fp16 lo*2048 (f16 dual-MFMA path)
  const float* W;
  unsigned short *Th, *Tl;
  int K, NOUT;
  if (idx < 49152) {
    idx -= 32768;
    W = W2; Th = W2t_hi; Tl = W2t_lo; K = 128; NOUT = 128;
  } else {
    idx -= 49152;
    W = W3; Th = W3t_hi; Tl = W3t_lo; K = 128; NOUT = 64;
  }
  int k = idx / NOUT, c = idx % NOUT;
  float v = W[idx];
  half_t h = (half_t)v;
  half_t l = (half_t)((v - (float)h) * 2048.0f);
  Th[(size_t)c * K + k] = __builtin_bit_cast(unsigned short, h);
  Tl[(size_t)c * K + k] = __builtin_bit_cast(unsigned short, l);
}

// ---------------- scan: sum 256 slices, exclusive prefix ----------------
__global__ __launch_bounds__(256) void scan_buckets(const int* __restrict__ bcnt_multi,
                                                    int* __restrict__ bbase,
                                                    int* __restrict__ bcur, int NB, int E) {
  __shared__ int tmp[256];
  int t = threadIdx.x;
  int v = 0;
  for (int h = 0; h < NHIST; ++h) v += bcnt_multi[h * 256 + t];
  tmp[t] = v;
  __syncthreads();
  for (int off = 1; off < 256; off <<= 1) {
    int x = (t >= off) ? tmp[t - off] : 0;
    __syncthreads();
    tmp[t] += x;
    __syncthreads();
  }
  int excl = tmp[t] - v;
  if (t < NB) { bbase[t] = excl; bcur[t] = excl; }
  if (t == 0) bbase[NB] = E;
}

// ---------------- scatter body (smem: 20480 B) ----------------
// record = (dst << 16) | src  (both < 65536)
__device__ __forceinline__ void scatter_body(char* smem_raw, int bid,
                                             const int* __restrict__ src,
                                             const int* __restrict__ dst,
                                             int* __restrict__ bcur,
                                             unsigned int* __restrict__ binned, int E) {
  unsigned int* recs = (unsigned int*)smem_raw;          // 16384 B
  int* hist = (int*)(smem_raw + 16384);
  int* lbase = hist + 256;
  int* resv = lbase + 256;
  int* cur = resv + 256;
  int t = threadIdx.x;
  int e0 = bid * CHUNK;
  if (e0 >= E) return;
  int len = min(CHUNK, E - e0);
  hist[t] = 0;
  cur[t] = 0;
  __syncthreads();
  for (int i = t; i < len; i += 256) atomicAdd(&hist[dst[e0 + i] >> 8], 1);
  __syncthreads();
  int v = hist[t];
  lbase[t] = v;
  __syncthreads();
  for (int off = 1; off < 256; off <<= 1) {
    int x = (t >= off) ? lbase[t - off] : 0;
    __syncthreads();
    lbase[t] += x;
    __syncthreads();
  }
  int myexcl = lbase[t] - v;
  if (v) resv[t] = atomicAdd(&bcur[t], v);
  __syncthreads();
  lbase[t] = myexcl;
  __syncthreads();
  for (int i = t; i < len; i += 256) {
    int d = dst[e0 + i], s = src[e0 + i];
    int b = d >> 8;
    int r = atomicAdd(&cur[b], 1);
    recs[lbase[b] + r] = ((unsigned int)d << 16) | (unsigned int)s;
  }
  __syncthreads();
  for (int i = t; i < len; i += 256) {
    unsigned int rc = recs[i];
    int b = rc >> 24;
    binned[resv[b] + (i - lbase[b])] = rc;
  }
}

// ---------------- sort body (smem: 36864 B) ----------------
__device__ __forceinline__ void sort_body(char* smem_raw, int b,
                                          const unsigned int* __restrict__ binned,
                                          const int* __restrict__ bbase,
                                          int* __restrict__ srcs,
                                          int* __restrict__ offs,
                                          float* __restrict__ dinv,
                                          int N, int NB, int E) {
  int* sstage = (int*)smem_raw;                           // 32768 B
  int* hist = (int*)(smem_raw + 32768);
  int* nbase = hist + 256;
  int* cur = nbase + 256;
  int* tmp = cur + 256;
  int t = threadIdx.x;
  int base = bbase[b], end = bbase[b + 1];
  int L = end - base;
  if (L > MAXB) L = MAXB;
  hist[t] = 0;
  __syncthreads();
  for (int i = t; i < L; i += 256)
    atomicAdd(&hist[(binned[base + i] >> 16) & 255], 1);
  __syncthreads();
  int v = hist[t];
  tmp[t] = v;
  __syncthreads();
  for (int off = 1; off < 256; off <<= 1) {
    int x = (t >= off) ? tmp[t - off] : 0;
    __syncthreads();
    tmp[t] += x;
    __syncthreads();
  }
  int excl = tmp[t] - v;
  nbase[t] = excl;
  cur[t] = excl;
  int node = (b << 8) + t;
  if (node < N) {
    offs[node] = base + excl;
    dinv[node] = rsqrtf(1.0f + (float)v);
  }
  if (b == NB - 1 && t == 0) offs[N] = E;
  __syncthreads();
  for (int i = t; i < L; i += 256) {
    unsigned int p = binned[base + i];
    int ld = (p >> 16) & 255;
    int slot = atomicAdd(&cur[ld], 1);
    sstage[slot] = (int)(p & 0xFFFFu);
  }
  __syncthreads();
  for (int i = t; i < L; i += 256) srcs[base + i] = sstage[i];
}

// ---------------- GEMM1 body: BM=32, bf16 hi/lo triple-MFMA, LN fused ------
template <int K, int NOUT, bool LN>
__device__ __forceinline__ void gemm_body(char* smem_raw, int gbid,
                                          const float* __restrict__ A,
                                          const unsigned short* __restrict__ Wt_hi,
                                          const unsigned short* __restrict__ Wt_lo,
                                          const float* __restrict__ gamma,
                                          const float* __restrict__ beta,
                                          half_t* __restrict__ out, int nrows) {
  constexpr int BM = 32, BK = 32, BKP = BK + 8;
  constexpr int NTW = NOUT / 32;

  const int tid = threadIdx.x;
  const int lane = tid & 63;
  const int w = tid >> 6;
  const int quad = lane >> 4;
  const int l16 = lane & 15;
  const int rg = (w & 1) * 16;
  const int cg = (w >> 1) * (NOUT / 2);
  const int row0 = gbid * BM;

  unsigned short* As_hi = (unsigned short*)smem_raw;
  unsigned short* As_lo = As_hi + BM * BKP;
  unsigned short* Bs_hi = As_lo + BM * BKP;
  unsigned short* Bs_lo = Bs_hi + NOUT * BKP;
  float* mu_s = (float*)(Bs_lo + NOUT * BKP);
  float* rs_s = mu_s + BM;

  if constexpr (LN) {
    int r = tid >> 3;
    int part = tid & 7;
    int grow = row0 + r;
    if (grow > nrows - 1) grow = nrows - 1;
    const float4* rp = (const float4*)(A + (size_t)grow * K);
    float s = 0.f, s2 = 0.f;
#pragma unroll
    for (int j = 0; j < K / 32; ++j) {
      float4 v = rp[part * (K / 32) + j];
      s += v.x + v.y + v.z + v.w;
      s2 += v.x * v.x + v.y * v.y + v.z * v.z + v.w * v.w;
    }
    s += __shfl_xor(s, 1);
    s += __shfl_xor(s, 2);
    s += __shfl_xor(s, 4);
    s2 += __shfl_xor(s2, 1);
    s2 += __shfl_xor(s2, 2);
    s2 += __shfl_xor(s2, 4);
    if (part == 0) {
      float m = s * (1.0f / (float)K);
      float var = s2 * (1.0f / (float)K) - m * m;
      mu_s[r] = m;
      rs_s[r] = rsqrtf(var + 1e-5f);
    }
    __syncthreads();
  }

  f32x4 acc[NTW];
#pragma unroll
  for (int t = 0; t < NTW; ++t) acc[t] = (f32x4){0.f, 0.f, 0.f, 0.f};

  for (int k0 = 0; k0 < K; k0 += BK) {
    {
      int r = tid >> 3;
      int c4 = (tid & 7) * 4;
      int grow = row0 + r;
      if (grow > nrows - 1) grow = nrows - 1;
      float4 v = *(const float4*)&A[(size_t)grow * K + k0 + c4];
      if constexpr (LN) {
        float m = mu_s[r], s = rs_s[r];
        float4 g = *(const float4*)&gamma[k0 + c4];
        float4 b = *(const float4*)&beta[k0 + c4];
        v.x = (v.x - m) * s * g.x + b.x;
        v.y = (v.y - m) * s * g.y + b.y;
        v.z = (v.z - m) * s * g.z + b.z;
        v.w = (v.w - m) * s * g.w + b.w;
      }
      float vv[4] = {v.x, v.y, v.z, v.w};
#pragma unroll
      for (int j = 0; j < 4; ++j) {
        __bf16 h = (__bf16)vv[j];
        __bf16 l = (__bf16)(vv[j] - (float)h);
        As_hi[r * BKP + c4 + j] = __builtin_bit_cast(unsigned short, h);
        As_lo[r * BKP + c4 + j] = __builtin_bit_cast(unsigned short, l);
      }
    }
#pragma unroll
    for (int i = 0; i < NOUT / 64; ++i) {
      int n = i * 64 + (tid >> 2);
      int c8 = (tid & 3) * 8;
      *(uint4*)&Bs_hi[n * BKP + c8] = *(const uint4*)&Wt_hi[(size_t)n * K + k0 + c8];
      *(uint4*)&Bs_lo[n * BKP + c8] = *(const uint4*)&Wt_lo[(size_t)n * K + k0 + c8];
    }
    __syncthreads();

    bf16x8 ah = *(const bf16x8*)&As_hi[(rg + l16) * BKP + quad * 8];
    bf16x8 al = *(const bf16x8*)&As_lo[(rg + l16) * BKP + quad * 8];
#pragma unroll
    for (int t = 0; t < NTW; ++t) {
      bf16x8 bh = *(const bf16x8*)&Bs_hi[(cg + t * 16 + l16) * BKP + quad * 8];
      bf16x8 bl = *(const bf16x8*)&Bs_lo[(cg + t * 16 + l16) * BKP + quad * 8];
      acc[t] = __builtin_amdgcn_mfma_f32_16x16x32_bf16(ah, bh, acc[t], 0, 0, 0);
      acc[t] = __builtin_amdgcn_mfma_f32_16x16x32_bf16(al, bh, acc[t], 0, 0, 0);
      acc[t] = __builtin_amdgcn_mfma_f32_16x16x32_bf16(ah, bl, acc[t], 0, 0, 0);
    }
    __syncthreads();
  }

#pragma unroll
  for (int t = 0; t < NTW; ++t) {
#pragma unroll
    for (int r = 0; r < 4; ++r) {
      int grow = row0 + rg + quad * 4 + r;
      if (grow < nrows)
        out[(size_t)grow * NOUT + cg + t * 16 + l16] = (half_t)acc[t][r];
    }
  }
}

constexpr int GEMM1_SMEM = 32 * 40 * 4 + 128 * 40 * 4 + 256;  // 25856

__global__ __launch_bounds__(256) void fused_scatter_gemm1(
    const int* __restrict__ src, const int* __restrict__ dst,
    int* __restrict__ bcur, unsigned int* __restrict__ binned, int E,
    const float* __restrict__ x,
    const unsigned short* __restrict__ W1t_hi, const unsigned short* __restrict__ W1t_lo,
    const float* __restrict__ gamma, const float* __restrict__ beta,
    half_t* __restrict__ t, int nrows, int nscat) {
  __shared__ __align__(16) char smem[GEMM1_SMEM];
  if ((int)blockIdx.x < nscat)
    scatter_body(smem, blockIdx.x, src, dst, bcur, binned, E);
  else
    gemm_body<256, 128, true>(smem, blockIdx.x - nscat, x, W1t_hi, W1t_lo,
                              gamma, beta, t, nrows);
}

__global__ __launch_bounds__(256) void fused_sort_gemm1(
    const unsigned int* __restrict__ binned, const int* __restrict__ bbase,
    int* __restrict__ srcs, int* __restrict__ offs, float* __restrict__ dinv,
    int N, int NB, int E,
    const float* __restrict__ x,
    const unsigned short* __restrict__ W1t_hi, const unsigned short* __restrict__ W1t_lo,
    const float* __restrict__ gamma, const float* __restrict__ beta,
    half_t* __restrict__ t, int nrows, int g1a) {
  __shared__ __align__(16) char smem[36864];
  if ((int)blockIdx.x < NB)
    sort_body(smem, blockIdx.x, binned, bbase, srcs, offs, dinv, N, NB, E);
  else
    gemm_body<256, 128, true>(smem, g1a + (blockIdx.x - NB), x, W1t_hi, W1t_lo,
                              gamma, beta, t, nrows);
}

// ---------------- fused agg + GEMM (layers 2/3) ----------------------------
// Aggregate 32 rows from tin (CSR gather, relu(di*acc + dii*self + bias))
// directly into the fp16 A-tile in LDS, then f16 dual-MFMA over K=128.
template <int NOUT>
__global__ __launch_bounds__(256) void agg_gemm(
    const half_t* __restrict__ tin,
    const int* __restrict__ offs, const int* __restrict__ srcs,
    const float* __restrict__ dinv, const float* __restrict__ bias,
    const unsigned short* __restrict__ Wt_hi,
    const unsigned short* __restrict__ Wt_lo,
    half_t* __restrict__ out, int nrows) {
  constexpr int K = 128, BK = 32, BKP = BK + 8, ROWP = K + 8;
  constexpr int NTW = NOUT / 32;
  __shared__ __align__(16) half_t As[32 * ROWP];        // 8704 B
  __shared__ __align__(16) half_t Bs_hi[NOUT * BKP];
  __shared__ __align__(16) half_t Bs_lo[NOUT * BKP];

  const int tid = threadIdx.x;
  const int row0 = blockIdx.x * 32;

  // ---- phase A: aggregate 32 rows into As ----
  {
    int g = tid >> 4, fl = tid & 15;
#pragma unroll
    for (int rr = g; rr < 32; rr += 16) {
      int node = row0 + rr;
      if (node > nrows - 1) node = nrows - 1;
      int e0 = offs[node], e1 = offs[node + 1];
      float acc[8] = {0.f, 0.f, 0.f, 0.f, 0.f, 0.f, 0.f, 0.f};
      int e = e0;
      for (; e + 3 < e1; e += 4) {
        int sa = srcs[e], sb = srcs[e + 1], sc = srcs[e + 2], sd = srcs[e + 3];
        float wa = dinv[sa], wb = dinv[sb], wc = dinv[sc], wd = dinv[sd];
        half8_t va = *(const half8_t*)(tin + ((size_t)sa << 7) + fl * 8);
        half8_t vb = *(const half8_t*)(tin + ((size_t)sb << 7) + fl * 8);
        half8_t vc = *(const half8_t*)(tin + ((size_t)sc << 7) + fl * 8);
        half8_t vd = *(const half8_t*)(tin + ((size_t)sd << 7) + fl * 8);
#pragma unroll
        for (int j = 0; j < 8; ++j) {
          acc[j] = fmaf(wa, (float)va[j], acc[j]);
          acc[j] = fmaf(wb, (float)vb[j], acc[j]);
          acc[j] = fmaf(wc, (float)vc[j], acc[j]);
          acc[j] = fmaf(wd, (float)vd[j], acc[j]);
        }
      }
      for (; e < e1; ++e) {
        int s = srcs[e];
        float w = dinv[s];
        half8_t v = *(const half8_t*)(tin + ((size_t)s << 7) + fl * 8);
#pragma unroll
        for (int j = 0; j < 8; ++j) acc[j] = fmaf(w, (float)v[j], acc[j]);
      }
      float di = dinv[node];
      float dii = di * di;
      half8_t sv = *(const half8_t*)(tin + ((size_t)node << 7) + fl * 8);
      float4 b0 = *(const float4*)(bias + fl * 8);
      float4 b1 = *(const float4*)(bias + fl * 8 + 4);
      float bb[8] = {b0.x, b0.y, b0.z, b0.w, b1.x, b1.y, b1.z, b1.w};
#pragma unroll
      for (int j = 0; j < 8; ++j) {
        float v = di * acc[j] + dii * (float)sv[j] + bb[j];
        As[rr * ROWP + fl * 8 + j] = (half_t)fmaxf(v, 0.f);
      }
    }
  }
  __syncthreads();

  // ---- phase B: f16 dual-MFMA GEMM, A from LDS ----
  const int lane = tid & 63;
  const int w = tid >> 6;
  const int quad = lane >> 4;
  const int l16 = lane & 15;
  const int rg = (w & 1) * 16;
  const int cg = (w >> 1) * (NOUT / 2);

  f32x4 acc1[NTW], acc2[NTW];
#pragma unroll
  for (int t = 0; t < NTW; ++t) {
    acc1[t] = (f32x4){0.f, 0.f, 0.f, 0.f};
    acc2[t] = (f32x4){0.f, 0.f, 0.f, 0.f};
  }

  for (int k0 = 0; k0 < K; k0 += BK) {
#pragma unroll
    for (int i = 0; i < NOUT / 64; ++i) {
      int n = i * 64 + (tid >> 2);
      int c8 = (tid & 3) * 8;
      *(uint4*)&Bs_hi[n * BKP + c8] = *(const uint4*)&Wt_hi[(size_t)n * K + k0 + c8];
      *(uint4*)&Bs_lo[n * BKP + c8] = *(const uint4*)&Wt_lo[(size_t)n * K + k0 + c8];
    }
    __syncthreads();

    half8_t av = *(const half8_t*)&As[(rg + l16) * ROWP + k0 + quad * 8];
#pragma unroll
    for (int t = 0; t < NTW; ++t) {
      half8_t bh = *(const half8_t*)&Bs_hi[(cg + t * 16 + l16) * BKP + quad * 8];
      half8_t bl = *(const half8_t*)&Bs_lo[(cg + t * 16 + l16) * BKP + quad * 8];
      acc1[t] = __builtin_amdgcn_mfma_f32_16x16x32_f16(av, bh, acc1[t], 0, 0, 0);
      acc2[t] = __builtin_amdgcn_mfma_f32_16x16x32_f16(av, bl, acc2[t], 0, 0, 0);
    }
    __syncthreads();
  }

#pragma unroll
  for (int t = 0; t < NTW; ++t) {
#pragma unroll
    for (int r = 0; r < 4; ++r) {
      int grow = row0 + rg + quad * 4 + r;
      if (grow < nrows)
        out[(size_t)grow * NOUT + cg + t * 16 + l16] =
            (half_t)(acc1[t][r] + acc2[t][r] * (1.0f / 2048.0f));
    }
  }
}

// ---------------- final aggregation (64-wide, fp32 out) --------------------
__global__ __launch_bounds__(256) void agg64_h(const half_t* __restrict__ t,
                                               const int* __restrict__ offs,
                                               const int* __restrict__ srcs,
                                               const float* __restrict__ dinv,
                                               const float* __restrict__ bias,
                                               float* __restrict__ out, int n) {
  int gid = blockIdx.x * blockDim.x + threadIdx.x;
  int node = gid >> 6, lane = gid & 63;
  if (node >= n) return;
  int og = lane >> 3;
  int fl = lane & 7;
  int e0 = offs[node], e1 = offs[node + 1];
  float acc[8] = {0.f, 0.f, 0.f, 0.f, 0.f, 0.f, 0.f, 0.f};
  int e = e0 + og;
  for (; e + 8 < e1; e += 16) {
    int sa = srcs[e], sb = srcs[e + 8];
    float wa = dinv[sa], wb = dinv[sb];
    half8_t va = *(const half8_t*)(t + ((size_t)sa << 6) + fl * 8);
    half8_t vb = *(const half8_t*)(t + ((size_t)sb << 6) + fl * 8);
#pragma unroll
    for (int j = 0; j < 8; ++j) {
      acc[j] = fmaf(wa, (float)va[j], acc[j]);
      acc[j] = fmaf(wb, (float)vb[j], acc[j]);
    }
  }
  for (; e < e1; e += 8) {
    int s = srcs[e];
    float w = dinv[s];
    half8_t v = *(const half8_t*)(t + ((size_t)s << 6) + fl * 8);
#pragma unroll
    for (int j = 0; j < 8; ++j) acc[j] = fmaf(w, (float)v[j], acc[j]);
  }
#pragma unroll
  for (int j = 0; j < 8; ++j) {
    acc[j] += __shfl_xor(acc[j], 8);
    acc[j] += __shfl_xor(acc[j], 16);
    acc[j] += __shfl_xor(acc[j], 32);
  }
  if (og == 0) {
    float di = dinv[node];
    float dii = di * di;
    half8_t sv = *(const half8_t*)(t + ((size_t)node << 6) + fl * 8);
    float4 b0 = *(const float4*)(bias + fl * 8);
    float4 b1 = *(const float4*)(bias + fl * 8 + 4);
    float bb[8] = {b0.x, b0.y, b0.z, b0.w, b1.x, b1.y, b1.z, b1.w};
    float ov[8];
#pragma unroll
    for (int j = 0; j < 8; ++j) ov[j] = di * acc[j] + dii * (float)sv[j] + bb[j];
    *(float4*)(out + ((size_t)node << 6) + fl * 8) = make_float4(ov[0], ov[1], ov[2], ov[3]);
    *(float4*)(out + ((size_t)node << 6) + fl * 8 + 4) = make_float4(ov[4], ov[5], ov[6], ov[7]);
  }
}

extern "C" void kernel_launch(void* const* d_in, const int* in_sizes, int n_in,
                              void* d_out, int out_size, void* d_ws, size_t ws_size,
                              hipStream_t stream) {
  const float* x = (const float*)d_in[0];
  const int* ei = (const int*)d_in[1];
  const float* gamma = (const float*)d_in[2];
  const float* beta = (const float*)d_in[3];
  const float* W1 = (const float*)d_in[4];
  const float* b1 = (const float*)d_in[5];
  const float* W2 = (const float*)d_in[6];
  const float* b2 = (const float*)d_in[7];
  const float* W3 = (const float*)d_in[8];
  const float* b3 = (const float*)d_in[9];
  float* out = (float*)d_out;

  const int N = in_sizes[0] / 256;  // 50000 < 65536: packed records valid
  const int E = in_sizes[1] / 2;
  const int* src = ei;
  const int* dst = ei + E;
  const int NB = (N + 255) >> 8;

  char* ws = (char*)d_ws;
  auto alloc = [&](size_t bytes) -> char* {
    char* p = ws;
    ws += (bytes + 255) & ~(size_t)255;
    return p;
  };
  int* bcnt_multi = (int*)alloc(NHIST * 256 * 4);
  int* bbase = (int*)alloc(257 * 4);
  int* bcur = (int*)alloc(256 * 4);
  unsigned int* binned = (unsigned int*)alloc((size_t)E * 4);
  int* srcs = (int*)alloc((size_t)E * 4);
  int* offs = (int*)alloc((size_t)(N + 1) * 4);
  float* dinv = (float*)alloc((size_t)N * 4);
  half_t* t = (half_t*)alloc((size_t)N * 128 * 2);
  half_t* h = (half_t*)alloc((size_t)N * 128 * 2);
  unsigned short* W1t_hi = (unsigned short*)alloc(256 * 128 * 2);
  unsigned short* W1t_lo = (unsigned short*)alloc(256 * 128 * 2);
  unsigned short* W2t_hi = (unsigned short*)alloc(128 * 128 * 2);
  unsigned short* W2t_lo = (unsigned short*)alloc(128 * 128 * 2);
  unsigned short* W3t_hi = (unsigned short*)alloc(128 * 64 * 2);
  unsigned short* W3t_lo = (unsigned short*)alloc(128 * 64 * 2);

  // ---- prep: hist x256 + wsplit x3 in one launch ----
  prep_misc<<<NHIST + 224, 256, 0, stream>>>(
      dst, W1, W2, W3, bcnt_multi, W1t_hi, W1t_lo, W2t_hi, W2t_lo,
      W3t_hi, W3t_lo, E);

  // ---- scan ----
  scan_buckets<<<1, 256, 0, stream>>>(bcnt_multi, bbase, bcur, NB, E);

  const int gemm_blocks = (N + 31) / 32;  // BM=32
  const int G1A = gemm_blocks / 2;
  const int G1B = gemm_blocks - G1A;
  const int NSCAT = (E + CHUNK - 1) / CHUNK;
  const int agg_blocks = (N + 3) / 4;

  // ---- CSR scatter ∥ GEMM1 (first half) ----
  fused_scatter_gemm1<<<NSCAT + G1A, 256, 0, stream>>>(
      src, dst, bcur, binned, E, x, W1t_hi, W1t_lo, gamma, beta, t, N, NSCAT);

  // ---- CSR sort ∥ GEMM1 (second half) ----
  fused_sort_gemm1<<<NB + G1B, 256, 0, stream>>>(
      binned, bbase, srcs, offs, dinv, N, NB, E, x, W1t_hi, W1t_lo, gamma, beta,
      t, N, G1A);

  // ---- layer 2: agg(t)+relu+b1 then @W2 -> h ----
  agg_gemm<128><<<gemm_blocks, 256, 0, stream>>>(
      t, offs, srcs, dinv, b1, W2t_hi, W2t_lo, h, N);

  // ---- layer 3: agg(h)+relu+b2 then @W3 -> t ----
  agg_gemm<64><<<gemm_blocks, 256, 0, stream>>>(
      h, offs, srcs, dinv, b2, W3t_hi, W3t_lo, t, N);

  // ---- final aggregation ----
  agg64_h<<<agg_blocks, 256, 0, stream>>>(t, offs, srcs, dinv, b3, out, N);
}